// Round 1
// 1085.631 us; speedup vs baseline: 1.6752x; 1.6752x over previous
//
#include <hip/hip_runtime.h>

#define N_NODES 16384
#define N_EDGES 65536
#define N_GRAPHS 64
#define HID 768
#define DDIM 256
#define HEADS 4

typedef __attribute__((ext_vector_type(8))) short bf16x8;   // 8 bf16 = 4 VGPR (MFMA A/B frag)
typedef __attribute__((ext_vector_type(4))) float f32x4;    // MFMA C/D frag

// ---------- helpers ----------
__device__ __forceinline__ float wave_reduce_sum(float v) {
#pragma unroll
    for (int off = 32; off; off >>= 1) v += __shfl_xor(v, off);
    return v;
}

__device__ __forceinline__ unsigned short f2bf(float f) {   // RNE fp32 -> bf16 bits
    unsigned u = __float_as_uint(f);
    return (unsigned short)((u + 0x7fffu + ((u >> 16) & 1u)) >> 16);
}
__device__ __forceinline__ float bf2f(unsigned short h) {
    return __uint_as_float((unsigned)h << 16);
}

// ---------- cosine relevance ----------
__global__ void rel_kernel(const float* __restrict__ text, const float* __restrict__ nodex,
                           const int* __restrict__ bid, float* __restrict__ rel) {
    int n = blockIdx.x * 4 + (threadIdx.x >> 6);
    int lane = threadIdx.x & 63;
    const float* t = text + (size_t)bid[n] * HID;
    const float* x = nodex + (size_t)n * HID;
    float num = 0.f, tt = 0.f, xx = 0.f;
#pragma unroll
    for (int i = 0; i < HID / 64; i++) {
        float tv = t[lane + i * 64], xv = x[lane + i * 64];
        num += tv * xv; tt += tv * tv; xx += xv * xv;
    }
    num = wave_reduce_sum(num);
    tt = wave_reduce_sum(tt);
    xx = wave_reduce_sum(xx);
    if (lane == 0) rel[n] = num / fmaxf(sqrtf(tt) * sqrtf(xx), 1e-8f);
}

// ---------- split conversions (3-term bf16 decomposition) ----------
// A-side blocks along K': (hi, lo, hi).  B-side blocks: (hi, hi, lo).
// => K'-GEMM computes Ahi@Bhi + Alo@Bhi + Ahi@Blo (error ~2^-17 rel).

// x [N_NODES,256] f32 -> xs [N_NODES, 768] bf16
__global__ void xconv_kernel(const float* __restrict__ x, unsigned short* __restrict__ xs) {
    int n = blockIdx.x * 4 + (threadIdx.x >> 6);
    int lane = threadIdx.x & 63;
    float4 a = ((const float4*)(x + (size_t)n * 256))[lane];
    ushort4 h = make_ushort4(f2bf(a.x), f2bf(a.y), f2bf(a.z), f2bf(a.w));
    ushort4 l = make_ushort4(f2bf(a.x - bf2f(h.x)), f2bf(a.y - bf2f(h.y)),
                             f2bf(a.z - bf2f(h.z)), f2bf(a.w - bf2f(h.w)));
    unsigned short* o = xs + (size_t)n * 768;
    ((ushort4*)(o))[lane] = h;
    ((ushort4*)(o + 256))[lane] = l;
    ((ushort4*)(o + 512))[lane] = h;
}

// nodex [N_NODES,768] * rel -> nfs [N_NODES, 2304] bf16
__global__ void nfconv_kernel(const float* __restrict__ nodex, const float* __restrict__ rel,
                              unsigned short* __restrict__ nfs) {
    int n = blockIdx.x;
    int t = threadIdx.x;
    float r = rel[n];
    unsigned short* o = nfs + (size_t)n * 2304;
#pragma unroll
    for (int j = 0; j < 3; j++) {
        int c = j * 256 + t;
        float a = nodex[(size_t)n * 768 + c] * r;
        unsigned short h = f2bf(a);
        unsigned short l = f2bf(a - bf2f(h));
        o[c] = h;
        o[768 + c] = l;
        o[1536 + c] = h;
    }
}

// W [K,N] f32 -> out [N, 3K] bf16 (transposed, B-side block order hi,hi,lo)
__global__ void wconv_kernel(const float* __restrict__ W, unsigned short* __restrict__ out,
                             int K, int N) {
    int k = blockIdx.x * 256 + threadIdx.x;
    int n = blockIdx.y;
    if (k >= K) return;
    float a = W[(size_t)k * N + n];
    unsigned short h = f2bf(a);
    unsigned short l = f2bf(a - bf2f(h));
    size_t o = (size_t)n * (3 * K);
    out[o + k] = h;
    out[o + K + k] = h;
    out[o + 2 * K + k] = l;
}

// ---------- MFMA GEMM: C[M,N] = A[M,Kp](bf16) @ B[N,Kp]^T(bf16) + bias ----------
// m97 structure: 128x128 tile, BK=64, 4 waves (2x2), 4x4 fragments of 16x16x32,
// global_load_lds width=16 staging, linear LDS, 2 barriers per K-step.
__global__ __launch_bounds__(256, 2) void gemm_mfma(
        const unsigned short* __restrict__ A,   // [M, Kp] row-major bf16
        const unsigned short* __restrict__ B,   // [N, Kp] row-major bf16 (= B^T)
        const float* __restrict__ bias,
        float* __restrict__ C, int N, int Kp) {
    __shared__ unsigned short As[128 * 64];     // [row][k] linear, 128B row
    __shared__ unsigned short Bs[128 * 64];
    const int tid = threadIdx.x;
    const int lane = tid & 63;
    const int wave = tid >> 6;
    const int wm = wave >> 1, wn = wave & 1;
    const int row0 = blockIdx.y * 128, col0 = blockIdx.x * 128;
    const int l15 = lane & 15, l16 = lane >> 4;

    f32x4 acc[4][4] = {};

    const char* Ac = (const char*)A;
    const char* Bc = (const char*)B;
    const size_t rowBytes = (size_t)Kp * 2;

    for (int k0 = 0; k0 < Kp; k0 += 64) {
        __syncthreads();                        // previous tile fully consumed
#pragma unroll
        for (int i = 0; i < 4; i++) {           // stage A: 16KB = 4 x (256 lanes x 16B)
            int o = i * 4096 + tid * 16;        // linear byte offset in tile
            int r = o >> 7, cb = o & 127;       // row / byte-in-row (64 bf16 = 128B)
            __builtin_amdgcn_global_load_lds(
                (const __attribute__((address_space(1))) void*)
                    (Ac + (size_t)(row0 + r) * rowBytes + (size_t)k0 * 2 + cb),
                (__attribute__((address_space(3))) void*)((char*)As + o), 16, 0, 0);
        }
#pragma unroll
        for (int i = 0; i < 4; i++) {           // stage B
            int o = i * 4096 + tid * 16;
            int r = o >> 7, cb = o & 127;
            __builtin_amdgcn_global_load_lds(
                (const __attribute__((address_space(1))) void*)
                    (Bc + (size_t)(col0 + r) * rowBytes + (size_t)k0 * 2 + cb),
                (__attribute__((address_space(3))) void*)((char*)Bs + o), 16, 0, 0);
        }
        __syncthreads();                        // compiler drains vmcnt(0) before barrier
#pragma unroll
        for (int kk = 0; kk < 2; kk++) {        // BK=64 = 2 x K32 MFMA steps
            bf16x8 af[4], bfr[4];
#pragma unroll
            for (int f = 0; f < 4; f++) {
                // A frag: lane holds row (l&15), k = (l>>4)*8 .. +8
                af[f]  = *(const bf16x8*)(As + ((wm * 64 + f * 16 + l15) * 64 + kk * 32 + l16 * 8));
                // B frag: lane holds col (l&15), same k-range (B^T rows)
                bfr[f] = *(const bf16x8*)(Bs + ((wn * 64 + f * 16 + l15) * 64 + kk * 32 + l16 * 8));
            }
#pragma unroll
            for (int fi = 0; fi < 4; fi++)
#pragma unroll
                for (int fj = 0; fj < 4; fj++)
                    acc[fi][fj] = __builtin_amdgcn_mfma_f32_16x16x32_bf16(
                        af[fi], bfr[fj], acc[fi][fj], 0, 0, 0);
        }
    }
    // epilogue: C/D layout col=lane&15, row=(lane>>4)*4+reg (m89-verified)
#pragma unroll
    for (int fj = 0; fj < 4; fj++) {
        int cc = col0 + wn * 64 + fj * 16 + l15;
        float bb = bias[cc];
#pragma unroll
        for (int fi = 0; fi < 4; fi++) {
            int rbase = row0 + wm * 64 + fi * 16 + l16 * 4;
#pragma unroll
            for (int r = 0; r < 4; r++)
                C[(size_t)(rbase + r) * N + cc] = acc[fi][fj][r] + bb;
        }
    }
}

// ---------- generic fp32 tiled GEMM (kept only for the tiny 64x256x768 tp GEMM) ----------
template<bool SCALE_A>
__global__ __launch_bounds__(256) void gemm_f32(
        const float* __restrict__ A, const float* __restrict__ B,
        const float* __restrict__ bias, const float* __restrict__ rowScale,
        float* __restrict__ C, int M, int N, int K) {
    const int BM = 64, BN = 64, BK = 16;
    __shared__ float As[BK][BM + 1];
    __shared__ float Bs[BK][BN + 1];
    int tid = threadIdx.x;
    int tx = tid & 15, ty = tid >> 4;
    int row0 = blockIdx.y * BM, col0 = blockIdx.x * BN;
    float acc[4][4] = {};
    for (int k0 = 0; k0 < K; k0 += BK) {
        {
            int c = tid & 15, r = tid >> 4;
#pragma unroll
            for (int i = 0; i < 4; i++) {
                int rr = r + 16 * i;
                float a = A[(size_t)(row0 + rr) * K + k0 + c];
                if (SCALE_A) a *= rowScale[row0 + rr];
                As[c][rr] = a;
            }
        }
        {
            int c = tid & 63, kr = tid >> 6;
#pragma unroll
            for (int i = 0; i < 4; i++) {
                int rr = kr + 4 * i;
                Bs[rr][c] = B[(size_t)(k0 + rr) * N + col0 + c];
            }
        }
        __syncthreads();
#pragma unroll
        for (int kk = 0; kk < BK; kk++) {
            float av[4], bv[4];
#pragma unroll
            for (int i = 0; i < 4; i++) av[i] = As[kk][ty * 4 + i];
#pragma unroll
            for (int j = 0; j < 4; j++) bv[j] = Bs[kk][tx * 4 + j];
#pragma unroll
            for (int i = 0; i < 4; i++)
#pragma unroll
                for (int j = 0; j < 4; j++)
                    acc[i][j] += av[i] * bv[j];
        }
        __syncthreads();
    }
#pragma unroll
    for (int i = 0; i < 4; i++) {
        int r = row0 + ty * 4 + i;
#pragma unroll
        for (int j = 0; j < 4; j++) {
            int c = col0 + tx * 4 + j;
            C[(size_t)r * N + c] = acc[i][j] + bias[c];
        }
    }
}

// ---------- CSR build ----------
__global__ void hist_kernel(const int* __restrict__ dst, int* __restrict__ cnt) {
    int e = blockIdx.x * 256 + threadIdx.x;
    if (e < N_EDGES) atomicAdd(&cnt[dst[e]], 1);
}

__global__ void scan_kernel(const int* __restrict__ cnt, int* __restrict__ base,
                            int* __restrict__ cursor) {
    int t = threadIdx.x;
    int s = 0;
    for (int i = 0; i < 64; i++) s += cnt[t * 64 + i];
    __shared__ int pref[256];
    pref[t] = s;
    __syncthreads();
    if (t == 0) {
        int a = 0;
        for (int i = 0; i < 256; i++) { int v = pref[i]; pref[i] = a; a += v; }
    }
    __syncthreads();
    int run = pref[t];
    for (int i = 0; i < 64; i++) {
        base[t * 64 + i] = run;
        cursor[t * 64 + i] = run;
        run += cnt[t * 64 + i];
    }
}

__global__ void scatter_kernel(const int* __restrict__ src, const int* __restrict__ dst,
                               int* __restrict__ cursor, int* __restrict__ esrc,
                               int* __restrict__ edst) {
    int e = blockIdx.x * 256 + threadIdx.x;
    if (e < N_EDGES) {
        int d = dst[e];
        int pos = atomicAdd(&cursor[d], 1);
        esrc[pos] = src[e];
        edst[pos] = d;
    }
}

// ---------- edge scores at CSR positions ----------
__global__ void score_csr_kernel(const float* __restrict__ q, const float* __restrict__ k,
                                 const int* __restrict__ esrc, const int* __restrict__ edst,
                                 float* __restrict__ sc) {
    int w = blockIdx.x * 4 + (threadIdx.x >> 6);
    int lane = threadIdx.x & 63;
    int pos = w >> 2, h = w & 3;
    int s = esrc[pos], d = edst[pos];
    float4 qa = ((const float4*)(q + (size_t)d * 1024 + h * 256))[lane];
    float4 ka = ((const float4*)(k + (size_t)s * 1024 + h * 256))[lane];
    float p = qa.x * ka.x + qa.y * ka.y + qa.z * ka.z + qa.w * ka.w;
    p = wave_reduce_sum(p);
    if (lane == 0) sc[(size_t)pos * 4 + h] = p * 0.0625f;  // 1/sqrt(256)
}

// ---------- per-node: softmax + alpha*v gather + head-mean + skip (+resid) + LN + ReLU ----------
template<bool RESID>
__global__ __launch_bounds__(256) void agg_norm_kernel(
        const float* __restrict__ v, const float* __restrict__ sc,
        const int* __restrict__ base, const int* __restrict__ cnt,
        const int* __restrict__ esrc, const float* __restrict__ hbuf,
        float* __restrict__ x, const float* __restrict__ gamma,
        const float* __restrict__ beta) {
    __shared__ float hacc[4][256];
    __shared__ float tmp[4];
    int n = blockIdx.x;
    int tid = threadIdx.x, lane = tid & 63, h = tid >> 6;
    int start = base[n], deg = cnt[n];

    float m = -1e30f;
    for (int i = 0; i < deg; i++) m = fmaxf(m, sc[(size_t)(start + i) * 4 + h]);
    if (deg == 0) m = 0.f;
    float den = 0.f;
    for (int i = 0; i < deg; i++) den += __expf(sc[(size_t)(start + i) * 4 + h] - m);
    float inv_den = 0.25f / (den + 1e-16f);

    float4 acc = {0.f, 0.f, 0.f, 0.f};
    for (int i = 0; i < deg; i++) {
        int s = esrc[start + i];
        float a = __expf(sc[(size_t)(start + i) * 4 + h] - m) * inv_den;
        float4 vv = ((const float4*)(v + (size_t)s * 1024 + h * 256))[lane];
        acc.x += a * vv.x; acc.y += a * vv.y; acc.z += a * vv.z; acc.w += a * vv.w;
    }
    ((float4*)&hacc[h][lane * 4])[0] = acc;
    __syncthreads();

    int c = tid;
    float val = hacc[0][c] + hacc[1][c] + hacc[2][c] + hacc[3][c] + hbuf[(size_t)n * 256 + c];
    if (RESID) val += x[(size_t)n * 256 + c];

    float s1 = wave_reduce_sum(val);
    if (lane == 0) tmp[h] = s1;
    __syncthreads();
    float mu = (tmp[0] + tmp[1] + tmp[2] + tmp[3]) * (1.0f / 256.0f);
    __syncthreads();
    float d = val - mu;
    float s2 = wave_reduce_sum(d * d);
    if (lane == 0) tmp[h] = s2;
    __syncthreads();
    float inv = rsqrtf((tmp[0] + tmp[1] + tmp[2] + tmp[3]) * (1.0f / 256.0f) + 1e-5f);
    x[(size_t)n * 256 + c] = fmaxf(d * inv * gamma[c] + beta[c], 0.f);
}

// ---------- pooling pass 1 ----------
__global__ void pool1_kernel(const float* __restrict__ x, const float* __restrict__ tp,
                             const int* __restrict__ bid, float* __restrict__ pstruct,
                             float* __restrict__ cntf, float* __restrict__ semden,
                             float* __restrict__ semex) {
    int n = blockIdx.x * 4 + (threadIdx.x >> 6);
    int lane = threadIdx.x & 63;
    int g = bid[n];
    float4 xv = ((const float4*)(x + (size_t)n * 256))[lane];
    float4 tv = ((const float4*)(tp + (size_t)g * 256))[lane];
    float p = wave_reduce_sum(xv.x * tv.x + xv.y * tv.y + xv.z * tv.z + xv.w * tv.w);
    float* ps = pstruct + (size_t)g * 256 + lane * 4;
    atomicAdd(ps + 0, xv.x); atomicAdd(ps + 1, xv.y);
    atomicAdd(ps + 2, xv.z); atomicAdd(ps + 3, xv.w);
    if (lane == 0) {
        float e = __expf(p);
        semex[n] = e;
        atomicAdd(&semden[g], e);
        atomicAdd(&cntf[g], 1.0f);
    }
}

// ---------- pooling pass 2 ----------
__global__ void pool2_kernel(const float* __restrict__ x, const int* __restrict__ bid,
                             const float* __restrict__ semden, const float* __restrict__ semex,
                             float* __restrict__ psem) {
    int n = blockIdx.x * 4 + (threadIdx.x >> 6);
    int lane = threadIdx.x & 63;
    int g = bid[n];
    float aw = semex[n] / (semden[g] + 1e-8f);
    float4 xv = ((const float4*)(x + (size_t)n * 256))[lane];
    float* ps = psem + (size_t)g * 256 + lane * 4;
    atomicAdd(ps + 0, xv.x * aw); atomicAdd(ps + 1, xv.y * aw);
    atomicAdd(ps + 2, xv.z * aw); atomicAdd(ps + 3, xv.w * aw);
}

// ---------- classifier ----------
__global__ void clf_kernel(const float* __restrict__ pstruct, const float* __restrict__ psem,
                           const float* __restrict__ cntf, const float* __restrict__ text,
                           const float* __restrict__ w, const float* __restrict__ b,
                           float* __restrict__ out) {
    int g = blockIdx.x * 4 + (threadIdx.x >> 6);
    int lane = threadIdx.x & 63;
    float invc = 1.0f / fmaxf(cntf[g], 1.0f);
    float acc = 0.f;
#pragma unroll
    for (int i = 0; i < 4; i++) { int c = lane + i * 64; acc += pstruct[(size_t)g * 256 + c] * invc * w[c]; }
#pragma unroll
    for (int i = 0; i < 4; i++) { int c = lane + i * 64; acc += psem[(size_t)g * 256 + c] * w[256 + c]; }
#pragma unroll
    for (int i = 0; i < 12; i++) { int c = lane + i * 64; acc += text[(size_t)g * 768 + c] * w[512 + c]; }
    acc = wave_reduce_sum(acc);
    if (lane == 0) out[g] = acc + b[0];
}

extern "C" void kernel_launch(void* const* d_in, const int* in_sizes, int n_in,
                              void* d_out, int out_size, void* d_ws, size_t ws_size,
                              hipStream_t stream) {
    const float* text  = (const float*)d_in[0];
    const float* nodex = (const float*)d_in[1];
    const float* Wp    = (const float*)d_in[2];
    const float* bp    = (const float*)d_in[3];
    const float* Wq    = (const float*)d_in[4];
    const float* bq    = (const float*)d_in[5];
    const float* Wk    = (const float*)d_in[6];
    const float* bk    = (const float*)d_in[7];
    const float* Wv    = (const float*)d_in[8];
    const float* bv    = (const float*)d_in[9];
    const float* Ws    = (const float*)d_in[10];
    const float* bs    = (const float*)d_in[11];
    const float* gamma = (const float*)d_in[12];
    const float* beta  = (const float*)d_in[13];
    const float* clfw  = (const float*)d_in[14];
    const float* clfb  = (const float*)d_in[15];
    const int*   eidx  = (const int*)d_in[16];
    const int*   bid   = (const int*)d_in[17];
    const int* src = eidx;
    const int* dst = eidx + N_EDGES;
    float* out = (float*)d_out;

    // workspace layout
    float* x     = (float*)d_ws;                     // 16384*256
    float* hbuf  = x + (size_t)N_NODES * 256;        // 16384*256
    float* qbuf  = hbuf + (size_t)N_NODES * 256;     // 16384*1024 (q, later v)
    float* kbuf  = qbuf + (size_t)N_NODES * 1024;    // 16384*1024
    float* rel   = kbuf + (size_t)N_NODES * 1024;    // 16384
    float* tp64  = rel + N_NODES;                    // 64*256
    float* sc    = tp64 + 64 * 256;                  // 65536*4
    int* esrc    = (int*)(sc + (size_t)N_EDGES * 4); // 65536
    int* edst    = esrc + N_EDGES;                   // 65536
    int* cnt     = edst + N_EDGES;                   // 16384
    int* base    = cnt + N_NODES;                    // 16384
    int* cursor  = base + N_NODES;                   // 16384
    float* semex = (float*)(cursor + N_NODES);       // 16384
    float* pstruct = semex + N_NODES;                // 64*256
    float* psem  = pstruct + 64 * 256;               // 64*256
    float* cntf  = psem + 64 * 256;                  // 64
    float* semden = cntf + 64;                       // 64
    // split-bf16 buffers
    unsigned short* xs  = (unsigned short*)(semden + 64);   // 16384*768
    unsigned short* Wqs = xs + (size_t)N_NODES * 768;       // 1024*768
    unsigned short* Wks = Wqs + 1024 * 768;                 // 1024*768
    unsigned short* Wvs = Wks + 1024 * 768;                 // 1024*768
    unsigned short* Wss = Wvs + 1024 * 768;                 // 256*768
    unsigned short* Wps = Wss + 256 * 768;                  // 256*2304
    // nfs [16384, 2304] aliases qbuf+kbuf (dead before qbuf is first written)
    unsigned short* nfs = (unsigned short*)qbuf;

    // relevance + CSR build
    rel_kernel<<<N_NODES / 4, 256, 0, stream>>>(text, nodex, bid, rel);
    hipMemsetAsync(cnt, 0, N_NODES * sizeof(int), stream);
    hist_kernel<<<N_EDGES / 256, 256, 0, stream>>>(dst, cnt);
    scan_kernel<<<1, 256, 0, stream>>>(cnt, base, cursor);
    scatter_kernel<<<N_EDGES / 256, 256, 0, stream>>>(src, dst, cursor, esrc, edst);

    // node projection via split-bf16 MFMA: nf = diag(rel)*nodex; x = nf @ Wp + bp
    nfconv_kernel<<<N_NODES, 256, 0, stream>>>(nodex, rel, nfs);
    wconv_kernel<<<dim3(HID / 256, DDIM), 256, 0, stream>>>(Wp, Wps, HID, DDIM);
    gemm_mfma<<<dim3(DDIM / 128, N_NODES / 128), 256, 0, stream>>>(
        nfs, Wps, bp, x, DDIM, 3 * HID);
    // tiny text projection stays fp32
    gemm_f32<false><<<dim3(DDIM / 64, 1), 256, 0, stream>>>(
        text, Wp, bp, nullptr, tp64, N_GRAPHS, DDIM, HID);

    for (int i = 0; i < 2; i++) {
        const float* Wqi = Wq + (size_t)i * DDIM * 1024;
        const float* Wki = Wk + (size_t)i * DDIM * 1024;
        const float* Wvi = Wv + (size_t)i * DDIM * 1024;
        const float* Wsi = Ws + (size_t)i * DDIM * DDIM;
        // weight splits (K=256 -> K'=768), x split
        wconv_kernel<<<dim3(1, 1024), 256, 0, stream>>>(Wqi, Wqs, DDIM, 1024);
        wconv_kernel<<<dim3(1, 1024), 256, 0, stream>>>(Wki, Wks, DDIM, 1024);
        wconv_kernel<<<dim3(1, 1024), 256, 0, stream>>>(Wvi, Wvs, DDIM, 1024);
        wconv_kernel<<<dim3(1, DDIM), 256, 0, stream>>>(Wsi, Wss, DDIM, DDIM);
        xconv_kernel<<<N_NODES / 4, 256, 0, stream>>>(x, xs);
        // skip connection into hbuf
        gemm_mfma<<<dim3(DDIM / 128, N_NODES / 128), 256, 0, stream>>>(
            xs, Wss, bs + i * DDIM, hbuf, DDIM, 768);
        // q, k
        gemm_mfma<<<dim3(1024 / 128, N_NODES / 128), 256, 0, stream>>>(
            xs, Wqs, bq + i * 1024, qbuf, 1024, 768);
        gemm_mfma<<<dim3(1024 / 128, N_NODES / 128), 256, 0, stream>>>(
            xs, Wks, bk + i * 1024, kbuf, 1024, 768);
        // scores at CSR positions
        score_csr_kernel<<<N_EDGES, 256, 0, stream>>>(qbuf, kbuf, esrc, edst, sc);
        // v (reuse qbuf; stream order guarantees score done first)
        gemm_mfma<<<dim3(1024 / 128, N_NODES / 128), 256, 0, stream>>>(
            xs, Wvs, bv + i * 1024, qbuf, 1024, 768);
        // softmax + gather + head-mean + skip + (resid) + LN + ReLU
        if (i == 0)
            agg_norm_kernel<true><<<N_NODES, 256, 0, stream>>>(
                qbuf, sc, base, cnt, esrc, hbuf, x, gamma, beta);
        else
            agg_norm_kernel<false><<<N_NODES, 256, 0, stream>>>(
                qbuf, sc, base, cnt, esrc, hbuf, x, gamma + 256, beta + 256);
    }

    // pools
    hipMemsetAsync(pstruct, 0, (size_t)(64 * 256 * 2 + 128) * sizeof(float), stream);
    pool1_kernel<<<N_NODES / 4, 256, 0, stream>>>(x, tp64, bid, pstruct, cntf, semden, semex);
    pool2_kernel<<<N_NODES / 4, 256, 0, stream>>>(x, bid, semden, semex, psem);
    clf_kernel<<<N_GRAPHS / 4, 256, 0, stream>>>(pstruct, psem, cntf, text, clfw, clfb, out);
}

// Round 2
// 907.317 us; speedup vs baseline: 2.0045x; 1.1965x over previous
//
#include <hip/hip_runtime.h>

#define N_NODES 16384
#define N_EDGES 65536
#define N_GRAPHS 64
#define HID 768
#define DDIM 256
#define HEADS 4

typedef __attribute__((ext_vector_type(8))) short bf16x8;   // 8 bf16 = 4 VGPR (MFMA A/B frag)
typedef __attribute__((ext_vector_type(4))) float f32x4;    // MFMA C/D frag

// ---------- helpers ----------
__device__ __forceinline__ float wave_reduce_sum(float v) {
#pragma unroll
    for (int off = 32; off; off >>= 1) v += __shfl_xor(v, off);
    return v;
}

__device__ __forceinline__ unsigned short f2bf(float f) {   // RNE fp32 -> bf16 bits
    unsigned u = __float_as_uint(f);
    return (unsigned short)((u + 0x7fffu + ((u >> 16) & 1u)) >> 16);
}
__device__ __forceinline__ float bf2f(unsigned short h) {
    return __uint_as_float((unsigned)h << 16);
}

// ---------- cosine relevance ----------
__global__ void rel_kernel(const float* __restrict__ text, const float* __restrict__ nodex,
                           const int* __restrict__ bid, float* __restrict__ rel) {
    int n = blockIdx.x * 4 + (threadIdx.x >> 6);
    int lane = threadIdx.x & 63;
    const float* t = text + (size_t)bid[n] * HID;
    const float* x = nodex + (size_t)n * HID;
    float num = 0.f, tt = 0.f, xx = 0.f;
#pragma unroll
    for (int i = 0; i < HID / 64; i++) {
        float tv = t[lane + i * 64], xv = x[lane + i * 64];
        num += tv * xv; tt += tv * tv; xx += xv * xv;
    }
    num = wave_reduce_sum(num);
    tt = wave_reduce_sum(tt);
    xx = wave_reduce_sum(xx);
    if (lane == 0) rel[n] = num / fmaxf(sqrtf(tt) * sqrtf(xx), 1e-8f);
}

// ---------- split conversions (3-term bf16 decomposition) ----------
// A-side blocks along K': (hi, lo, hi).  B-side blocks: (hi, hi, lo).
// => K'-GEMM computes Ahi@Bhi + Alo@Bhi + Ahi@Blo (error ~2^-17 rel).

// x [N_NODES,256] f32 -> xs [N_NODES, 768] bf16
__global__ void xconv_kernel(const float* __restrict__ x, unsigned short* __restrict__ xs) {
    int n = blockIdx.x * 4 + (threadIdx.x >> 6);
    int lane = threadIdx.x & 63;
    float4 a = ((const float4*)(x + (size_t)n * 256))[lane];
    ushort4 h = make_ushort4(f2bf(a.x), f2bf(a.y), f2bf(a.z), f2bf(a.w));
    ushort4 l = make_ushort4(f2bf(a.x - bf2f(h.x)), f2bf(a.y - bf2f(h.y)),
                             f2bf(a.z - bf2f(h.z)), f2bf(a.w - bf2f(h.w)));
    unsigned short* o = xs + (size_t)n * 768;
    ((ushort4*)(o))[lane] = h;
    ((ushort4*)(o + 256))[lane] = l;
    ((ushort4*)(o + 512))[lane] = h;
}

// nodex [N_NODES,768] * rel -> nfs [N_NODES, 2304] bf16
__global__ void nfconv_kernel(const float* __restrict__ nodex, const float* __restrict__ rel,
                              unsigned short* __restrict__ nfs) {
    int n = blockIdx.x;
    int t = threadIdx.x;
    float r = rel[n];
    unsigned short* o = nfs + (size_t)n * 2304;
#pragma unroll
    for (int j = 0; j < 3; j++) {
        int c = j * 256 + t;
        float a = nodex[(size_t)n * 768 + c] * r;
        unsigned short h = f2bf(a);
        unsigned short l = f2bf(a - bf2f(h));
        o[c] = h;
        o[768 + c] = l;
        o[1536 + c] = h;
    }
}

// W [K,N] f32 -> out [N, 3K] bf16 (transposed, B-side block order hi,hi,lo)
__global__ void wconv_kernel(const float* __restrict__ W, unsigned short* __restrict__ out,
                             int K, int N) {
    int k = blockIdx.x * 256 + threadIdx.x;
    int n = blockIdx.y;
    if (k >= K) return;
    float a = W[(size_t)k * N + n];
    unsigned short h = f2bf(a);
    unsigned short l = f2bf(a - bf2f(h));
    size_t o = (size_t)n * (3 * K);
    out[o + k] = h;
    out[o + K + k] = h;
    out[o + 2 * K + k] = l;
}

// ---------- MFMA GEMM: C[M,N] = A[M,Kp](bf16) @ B[N,Kp]^T(bf16) + bias ----------
__global__ __launch_bounds__(256, 2) void gemm_mfma(
        const unsigned short* __restrict__ A,   // [M, Kp] row-major bf16
        const unsigned short* __restrict__ B,   // [N, Kp] row-major bf16 (= B^T)
        const float* __restrict__ bias,
        float* __restrict__ C, int N, int Kp) {
    __shared__ unsigned short As[128 * 64];     // [row][k] linear, 128B row
    __shared__ unsigned short Bs[128 * 64];
    const int tid = threadIdx.x;
    const int lane = tid & 63;
    const int wave = tid >> 6;
    const int wm = wave >> 1, wn = wave & 1;
    const int row0 = blockIdx.y * 128, col0 = blockIdx.x * 128;
    const int l15 = lane & 15, l16 = lane >> 4;

    f32x4 acc[4][4] = {};

    const char* Ac = (const char*)A;
    const char* Bc = (const char*)B;
    const size_t rowBytes = (size_t)Kp * 2;

    for (int k0 = 0; k0 < Kp; k0 += 64) {
        __syncthreads();
#pragma unroll
        for (int i = 0; i < 4; i++) {           // stage A: 16KB
            int o = i * 4096 + tid * 16;
            int r = o >> 7, cb = o & 127;
            __builtin_amdgcn_global_load_lds(
                (const __attribute__((address_space(1))) void*)
                    (Ac + (size_t)(row0 + r) * rowBytes + (size_t)k0 * 2 + cb),
                (__attribute__((address_space(3))) void*)((char*)As + o), 16, 0, 0);
        }
#pragma unroll
        for (int i = 0; i < 4; i++) {           // stage B
            int o = i * 4096 + tid * 16;
            int r = o >> 7, cb = o & 127;
            __builtin_amdgcn_global_load_lds(
                (const __attribute__((address_space(1))) void*)
                    (Bc + (size_t)(col0 + r) * rowBytes + (size_t)k0 * 2 + cb),
                (__attribute__((address_space(3))) void*)((char*)Bs + o), 16, 0, 0);
        }
        __syncthreads();
#pragma unroll
        for (int kk = 0; kk < 2; kk++) {
            bf16x8 af[4], bfr[4];
#pragma unroll
            for (int f = 0; f < 4; f++) {
                af[f]  = *(const bf16x8*)(As + ((wm * 64 + f * 16 + l15) * 64 + kk * 32 + l16 * 8));
                bfr[f] = *(const bf16x8*)(Bs + ((wn * 64 + f * 16 + l15) * 64 + kk * 32 + l16 * 8));
            }
#pragma unroll
            for (int fi = 0; fi < 4; fi++)
#pragma unroll
                for (int fj = 0; fj < 4; fj++)
                    acc[fi][fj] = __builtin_amdgcn_mfma_f32_16x16x32_bf16(
                        af[fi], bfr[fj], acc[fi][fj], 0, 0, 0);
        }
    }
#pragma unroll
    for (int fj = 0; fj < 4; fj++) {
        int cc = col0 + wn * 64 + fj * 16 + l15;
        float bb = bias[cc];
#pragma unroll
        for (int fi = 0; fi < 4; fi++) {
            int rbase = row0 + wm * 64 + fi * 16 + l16 * 4;
#pragma unroll
            for (int r = 0; r < 4; r++)
                C[(size_t)(rbase + r) * N + cc] = acc[fi][fj][r] + bb;
        }
    }
}

// ---------- generic fp32 tiled GEMM (tiny 64x256x768 tp GEMM only) ----------
template<bool SCALE_A>
__global__ __launch_bounds__(256) void gemm_f32(
        const float* __restrict__ A, const float* __restrict__ B,
        const float* __restrict__ bias, const float* __restrict__ rowScale,
        float* __restrict__ C, int M, int N, int K) {
    const int BM = 64, BN = 64, BK = 16;
    __shared__ float As[BK][BM + 1];
    __shared__ float Bs[BK][BN + 1];
    int tid = threadIdx.x;
    int tx = tid & 15, ty = tid >> 4;
    int row0 = blockIdx.y * BM, col0 = blockIdx.x * BN;
    float acc[4][4] = {};
    for (int k0 = 0; k0 < K; k0 += BK) {
        {
            int c = tid & 15, r = tid >> 4;
#pragma unroll
            for (int i = 0; i < 4; i++) {
                int rr = r + 16 * i;
                float a = A[(size_t)(row0 + rr) * K + k0 + c];
                if (SCALE_A) a *= rowScale[row0 + rr];
                As[c][rr] = a;
            }
        }
        {
            int c = tid & 63, kr = tid >> 6;
#pragma unroll
            for (int i = 0; i < 4; i++) {
                int rr = kr + 4 * i;
                Bs[rr][c] = B[(size_t)(k0 + rr) * N + col0 + c];
            }
        }
        __syncthreads();
#pragma unroll
        for (int kk = 0; kk < BK; kk++) {
            float av[4], bv[4];
#pragma unroll
            for (int i = 0; i < 4; i++) av[i] = As[kk][ty * 4 + i];
#pragma unroll
            for (int j = 0; j < 4; j++) bv[j] = Bs[kk][tx * 4 + j];
#pragma unroll
            for (int i = 0; i < 4; i++)
#pragma unroll
                for (int j = 0; j < 4; j++)
                    acc[i][j] += av[i] * bv[j];
        }
        __syncthreads();
    }
#pragma unroll
    for (int i = 0; i < 4; i++) {
        int r = row0 + ty * 4 + i;
#pragma unroll
        for (int j = 0; j < 4; j++) {
            int c = col0 + tx * 4 + j;
            C[(size_t)r * N + c] = acc[i][j] + bias[c];
        }
    }
}

// ---------- CSR build ----------
__global__ void hist_kernel(const int* __restrict__ dst, int* __restrict__ cnt) {
    int e = blockIdx.x * 256 + threadIdx.x;
    if (e < N_EDGES) atomicAdd(&cnt[dst[e]], 1);
}

__global__ void scan_kernel(const int* __restrict__ cnt, int* __restrict__ base,
                            int* __restrict__ cursor) {
    int t = threadIdx.x;
    int s = 0;
    for (int i = 0; i < 64; i++) s += cnt[t * 64 + i];
    __shared__ int pref[256];
    pref[t] = s;
    __syncthreads();
    if (t == 0) {
        int a = 0;
        for (int i = 0; i < 256; i++) { int v = pref[i]; pref[i] = a; a += v; }
    }
    __syncthreads();
    int run = pref[t];
    for (int i = 0; i < 64; i++) {
        base[t * 64 + i] = run;
        cursor[t * 64 + i] = run;
        run += cnt[t * 64 + i];
    }
}

__global__ void scatter_kernel(const int* __restrict__ src, const int* __restrict__ dst,
                               int* __restrict__ cursor, int* __restrict__ esrc,
                               int* __restrict__ edst) {
    int e = blockIdx.x * 256 + threadIdx.x;
    if (e < N_EDGES) {
        int d = dst[e];
        int pos = atomicAdd(&cursor[d], 1);
        esrc[pos] = src[e];
        edst[pos] = d;
    }
}

// ---------- graph segment boundaries (batch_ids is sorted) ----------
__global__ void gbounds_kernel(const int* __restrict__ bid, int* __restrict__ gstart) {
    int g = threadIdx.x;
    if (g > N_GRAPHS) return;
    int lo = 0, hi = N_NODES;
    while (lo < hi) { int mid = (lo + hi) >> 1; if (bid[mid] < g) lo = mid + 1; else hi = mid; }
    gstart[g] = lo;
}

// ---------- edge scores at CSR positions ----------
__global__ void score_csr_kernel(const float* __restrict__ q, const float* __restrict__ k,
                                 const int* __restrict__ esrc, const int* __restrict__ edst,
                                 float* __restrict__ sc) {
    int w = blockIdx.x * 4 + (threadIdx.x >> 6);
    int lane = threadIdx.x & 63;
    int pos = w >> 2, h = w & 3;
    int s = esrc[pos], d = edst[pos];
    float4 qa = ((const float4*)(q + (size_t)d * 1024 + h * 256))[lane];
    float4 ka = ((const float4*)(k + (size_t)s * 1024 + h * 256))[lane];
    float p = qa.x * ka.x + qa.y * ka.y + qa.z * ka.z + qa.w * ka.w;
    p = wave_reduce_sum(p);
    if (lane == 0) sc[(size_t)pos * 4 + h] = p * 0.0625f;  // 1/sqrt(256)
}

// ---------- per-node: softmax + alpha*v gather + head-mean + skip (+resid) + LN + ReLU ----------
template<bool RESID>
__global__ __launch_bounds__(256) void agg_norm_kernel(
        const float* __restrict__ v, const float* __restrict__ sc,
        const int* __restrict__ base, const int* __restrict__ cnt,
        const int* __restrict__ esrc, const float* __restrict__ hbuf,
        float* __restrict__ x, const float* __restrict__ gamma,
        const float* __restrict__ beta) {
    __shared__ float hacc[4][256];
    __shared__ float tmp[4];
    int n = blockIdx.x;
    int tid = threadIdx.x, lane = tid & 63, h = tid >> 6;
    int start = base[n], deg = cnt[n];

    float m = -1e30f;
    for (int i = 0; i < deg; i++) m = fmaxf(m, sc[(size_t)(start + i) * 4 + h]);
    if (deg == 0) m = 0.f;
    float den = 0.f;
    for (int i = 0; i < deg; i++) den += __expf(sc[(size_t)(start + i) * 4 + h] - m);
    float inv_den = 0.25f / (den + 1e-16f);

    float4 acc = {0.f, 0.f, 0.f, 0.f};
    for (int i = 0; i < deg; i++) {
        int s = esrc[start + i];
        float a = __expf(sc[(size_t)(start + i) * 4 + h] - m) * inv_den;
        float4 vv = ((const float4*)(v + (size_t)s * 1024 + h * 256))[lane];
        acc.x += a * vv.x; acc.y += a * vv.y; acc.z += a * vv.z; acc.w += a * vv.w;
    }
    ((float4*)&hacc[h][lane * 4])[0] = acc;
    __syncthreads();

    int c = tid;
    float val = hacc[0][c] + hacc[1][c] + hacc[2][c] + hacc[3][c] + hbuf[(size_t)n * 256 + c];
    if (RESID) val += x[(size_t)n * 256 + c];

    float s1 = wave_reduce_sum(val);
    if (lane == 0) tmp[h] = s1;
    __syncthreads();
    float mu = (tmp[0] + tmp[1] + tmp[2] + tmp[3]) * (1.0f / 256.0f);
    __syncthreads();
    float d = val - mu;
    float s2 = wave_reduce_sum(d * d);
    if (lane == 0) tmp[h] = s2;
    __syncthreads();
    float inv = rsqrtf((tmp[0] + tmp[1] + tmp[2] + tmp[3]) * (1.0f / 256.0f) + 1e-5f);
    x[(size_t)n * 256 + c] = fmaxf(d * inv * gamma[c] + beta[c], 0.f);
}

// ---------- pooling pass 1 (segmented, low-contention) ----------
// 4 blocks per graph; each wave accumulates full 256-channel sum (float4/lane).
__global__ __launch_bounds__(256) void pool1_seg(
        const float* __restrict__ x, const float* __restrict__ tp,
        const int* __restrict__ gstart, float* __restrict__ pstruct,
        float* __restrict__ semden, float* __restrict__ semex) {
    int g = blockIdx.x >> 2, q = blockIdx.x & 3;
    int s0 = gstart[g], s1 = gstart[g + 1];
    int chunk = (s1 - s0 + 3) >> 2;
    int a = s0 + q * chunk, b = min(a + chunk, s1);
    int wave = threadIdx.x >> 6, lane = threadIdx.x & 63;
    float4 tv = ((const float4*)(tp + (size_t)g * 256))[lane];
    float4 acc = {0.f, 0.f, 0.f, 0.f};
    float esum = 0.f;
    for (int n = a + wave; n < b; n += 4) {
        float4 xv = ((const float4*)(x + (size_t)n * 256))[lane];
        float p = wave_reduce_sum(xv.x * tv.x + xv.y * tv.y + xv.z * tv.z + xv.w * tv.w);
        float e = __expf(p);          // wave-uniform after butterfly reduce
        if (lane == 0) semex[n] = e;
        esum += e;
        acc.x += xv.x; acc.y += xv.y; acc.z += xv.z; acc.w += xv.w;
    }
    __shared__ float sacc[4][256];
    __shared__ float tse[4];
    ((float4*)&sacc[wave][lane * 4])[0] = acc;
    if (lane == 0) tse[wave] = esum;
    __syncthreads();
    int c = threadIdx.x;
    float v = sacc[0][c] + sacc[1][c] + sacc[2][c] + sacc[3][c];
    atomicAdd(&pstruct[(size_t)g * 256 + c], v);
    if (threadIdx.x == 0)
        atomicAdd(&semden[g], tse[0] + tse[1] + tse[2] + tse[3]);
}

// ---------- pooling pass 2 (segmented, low-contention) ----------
__global__ __launch_bounds__(256) void pool2_seg(
        const float* __restrict__ x, const int* __restrict__ gstart,
        const float* __restrict__ semden, const float* __restrict__ semex,
        float* __restrict__ psem) {
    int g = blockIdx.x >> 2, q = blockIdx.x & 3;
    int s0 = gstart[g], s1 = gstart[g + 1];
    int chunk = (s1 - s0 + 3) >> 2;
    int a = s0 + q * chunk, b = min(a + chunk, s1);
    int wave = threadIdx.x >> 6, lane = threadIdx.x & 63;
    float inv = 1.0f / (semden[g] + 1e-8f);
    float4 acc = {0.f, 0.f, 0.f, 0.f};
    for (int n = a + wave; n < b; n += 4) {
        float aw = semex[n] * inv;
        float4 xv = ((const float4*)(x + (size_t)n * 256))[lane];
        acc.x += xv.x * aw; acc.y += xv.y * aw; acc.z += xv.z * aw; acc.w += xv.w * aw;
    }
    __shared__ float sacc[4][256];
    ((float4*)&sacc[wave][lane * 4])[0] = acc;
    __syncthreads();
    int c = threadIdx.x;
    float v = sacc[0][c] + sacc[1][c] + sacc[2][c] + sacc[3][c];
    atomicAdd(&psem[(size_t)g * 256 + c], v);
}

// ---------- classifier ----------
__global__ void clf_kernel(const float* __restrict__ pstruct, const float* __restrict__ psem,
                           const int* __restrict__ gstart, const float* __restrict__ text,
                           const float* __restrict__ w, const float* __restrict__ b,
                           float* __restrict__ out) {
    int g = blockIdx.x * 4 + (threadIdx.x >> 6);
    int lane = threadIdx.x & 63;
    float invc = 1.0f / fmaxf((float)(gstart[g + 1] - gstart[g]), 1.0f);
    float acc = 0.f;
#pragma unroll
    for (int i = 0; i < 4; i++) { int c = lane + i * 64; acc += pstruct[(size_t)g * 256 + c] * invc * w[c]; }
#pragma unroll
    for (int i = 0; i < 4; i++) { int c = lane + i * 64; acc += psem[(size_t)g * 256 + c] * w[256 + c]; }
#pragma unroll
    for (int i = 0; i < 12; i++) { int c = lane + i * 64; acc += text[(size_t)g * 768 + c] * w[512 + c]; }
    acc = wave_reduce_sum(acc);
    if (lane == 0) out[g] = acc + b[0];
}

extern "C" void kernel_launch(void* const* d_in, const int* in_sizes, int n_in,
                              void* d_out, int out_size, void* d_ws, size_t ws_size,
                              hipStream_t stream) {
    const float* text  = (const float*)d_in[0];
    const float* nodex = (const float*)d_in[1];
    const float* Wp    = (const float*)d_in[2];
    const float* bp    = (const float*)d_in[3];
    const float* Wq    = (const float*)d_in[4];
    const float* bq    = (const float*)d_in[5];
    const float* Wk    = (const float*)d_in[6];
    const float* bk    = (const float*)d_in[7];
    const float* Wv    = (const float*)d_in[8];
    const float* bv    = (const float*)d_in[9];
    const float* Ws    = (const float*)d_in[10];
    const float* bs    = (const float*)d_in[11];
    const float* gamma = (const float*)d_in[12];
    const float* beta  = (const float*)d_in[13];
    const float* clfw  = (const float*)d_in[14];
    const float* clfb  = (const float*)d_in[15];
    const int*   eidx  = (const int*)d_in[16];
    const int*   bid   = (const int*)d_in[17];
    const int* src = eidx;
    const int* dst = eidx + N_EDGES;
    float* out = (float*)d_out;

    // workspace layout
    float* x     = (float*)d_ws;                     // 16384*256
    float* hbuf  = x + (size_t)N_NODES * 256;        // 16384*256
    float* qbuf  = hbuf + (size_t)N_NODES * 256;     // 16384*1024 (q, later v)
    float* kbuf  = qbuf + (size_t)N_NODES * 1024;    // 16384*1024
    float* rel   = kbuf + (size_t)N_NODES * 1024;    // 16384
    float* tp64  = rel + N_NODES;                    // 64*256
    float* sc    = tp64 + 64 * 256;                  // 65536*4
    int* esrc    = (int*)(sc + (size_t)N_EDGES * 4); // 65536
    int* edst    = esrc + N_EDGES;                   // 65536
    int* cnt     = edst + N_EDGES;                   // 16384
    int* base    = cnt + N_NODES;                    // 16384
    int* cursor  = base + N_NODES;                   // 16384
    float* semex = (float*)(cursor + N_NODES);       // 16384
    float* pstruct = semex + N_NODES;                // 64*256
    float* psem  = pstruct + 64 * 256;               // 64*256
    float* cntf  = psem + 64 * 256;                  // 64 (unused, layout pad)
    float* semden = cntf + 64;                       // 64
    int* gstart  = (int*)(semden + 64);              // 80 (65 used, 16B-align pad)
    // split-bf16 buffers
    unsigned short* xs  = (unsigned short*)(gstart + 80);   // 16384*768
    unsigned short* Wqs = xs + (size_t)N_NODES * 768;       // 1024*768
    unsigned short* Wks = Wqs + 1024 * 768;                 // 1024*768
    unsigned short* Wvs = Wks + 1024 * 768;                 // 1024*768
    unsigned short* Wss = Wvs + 1024 * 768;                 // 256*768
    unsigned short* Wps = Wss + 256 * 768;                  // 256*2304
    // nfs [16384, 2304] aliases qbuf+kbuf (dead before qbuf is first written)
    unsigned short* nfs = (unsigned short*)qbuf;

    // relevance + CSR build + graph bounds
    rel_kernel<<<N_NODES / 4, 256, 0, stream>>>(text, nodex, bid, rel);
    hipMemsetAsync(cnt, 0, N_NODES * sizeof(int), stream);
    hist_kernel<<<N_EDGES / 256, 256, 0, stream>>>(dst, cnt);
    scan_kernel<<<1, 256, 0, stream>>>(cnt, base, cursor);
    scatter_kernel<<<N_EDGES / 256, 256, 0, stream>>>(src, dst, cursor, esrc, edst);
    gbounds_kernel<<<1, 128, 0, stream>>>(bid, gstart);

    // node projection via split-bf16 MFMA: nf = diag(rel)*nodex; x = nf @ Wp + bp
    nfconv_kernel<<<N_NODES, 256, 0, stream>>>(nodex, rel, nfs);
    wconv_kernel<<<dim3(HID / 256, DDIM), 256, 0, stream>>>(Wp, Wps, HID, DDIM);
    gemm_mfma<<<dim3(DDIM / 128, N_NODES / 128), 256, 0, stream>>>(
        nfs, Wps, bp, x, DDIM, 3 * HID);
    // tiny text projection stays fp32
    gemm_f32<false><<<dim3(DDIM / 64, 1), 256, 0, stream>>>(
        text, Wp, bp, nullptr, tp64, N_GRAPHS, DDIM, HID);

    for (int i = 0; i < 2; i++) {
        const float* Wqi = Wq + (size_t)i * DDIM * 1024;
        const float* Wki = Wk + (size_t)i * DDIM * 1024;
        const float* Wvi = Wv + (size_t)i * DDIM * 1024;
        const float* Wsi = Ws + (size_t)i * DDIM * DDIM;
        // weight splits (K=256 -> K'=768), x split
        wconv_kernel<<<dim3(1, 1024), 256, 0, stream>>>(Wqi, Wqs, DDIM, 1024);
        wconv_kernel<<<dim3(1, 1024), 256, 0, stream>>>(Wki, Wks, DDIM, 1024);
        wconv_kernel<<<dim3(1, 1024), 256, 0, stream>>>(Wvi, Wvs, DDIM, 1024);
        wconv_kernel<<<dim3(1, DDIM), 256, 0, stream>>>(Wsi, Wss, DDIM, DDIM);
        xconv_kernel<<<N_NODES / 4, 256, 0, stream>>>(x, xs);
        // skip connection into hbuf
        gemm_mfma<<<dim3(DDIM / 128, N_NODES / 128), 256, 0, stream>>>(
            xs, Wss, bs + i * DDIM, hbuf, DDIM, 768);
        // q, k
        gemm_mfma<<<dim3(1024 / 128, N_NODES / 128), 256, 0, stream>>>(
            xs, Wqs, bq + i * 1024, qbuf, 1024, 768);
        gemm_mfma<<<dim3(1024 / 128, N_NODES / 128), 256, 0, stream>>>(
            xs, Wks, bk + i * 1024, kbuf, 1024, 768);
        // scores at CSR positions
        score_csr_kernel<<<N_EDGES, 256, 0, stream>>>(qbuf, kbuf, esrc, edst, sc);
        // v (reuse qbuf; stream order guarantees score done first)
        gemm_mfma<<<dim3(1024 / 128, N_NODES / 128), 256, 0, stream>>>(
            xs, Wvs, bv + i * 1024, qbuf, 1024, 768);
        // softmax + gather + head-mean + skip + (resid) + LN + ReLU
        if (i == 0)
            agg_norm_kernel<true><<<N_NODES, 256, 0, stream>>>(
                qbuf, sc, base, cnt, esrc, hbuf, x, gamma, beta);
        else
            agg_norm_kernel<false><<<N_NODES, 256, 0, stream>>>(
                qbuf, sc, base, cnt, esrc, hbuf, x, gamma + 256, beta + 256);
    }

    // pools (segmented, 4 blocks/graph; atomics only for 4-way combine)
    hipMemsetAsync(pstruct, 0, (size_t)(64 * 256 * 2 + 128) * sizeof(float), stream);
    pool1_seg<<<N_GRAPHS * 4, 256, 0, stream>>>(x, tp64, gstart, pstruct, semden, semex);
    pool2_seg<<<N_GRAPHS * 4, 256, 0, stream>>>(x, gstart, semden, semex, psem);
    clf_kernel<<<N_GRAPHS / 4, 256, 0, stream>>>(pstruct, psem, gstart, clfw ? text : text, clfw, clfb, out);
}

// Round 3
// 747.106 us; speedup vs baseline: 2.4343x; 1.2144x over previous
//
#include <hip/hip_runtime.h>

#define N_NODES 16384
#define N_EDGES 65536
#define N_GRAPHS 64
#define HID 768
#define DDIM 256
#define HEADS 4

typedef __attribute__((ext_vector_type(8))) short bf16x8;   // 8 bf16 = 4 VGPR (MFMA A/B frag)
typedef __attribute__((ext_vector_type(4))) float f32x4;    // MFMA C/D frag

// ---------- helpers ----------
__device__ __forceinline__ float wave_reduce_sum(float v) {
#pragma unroll
    for (int off = 32; off; off >>= 1) v += __shfl_xor(v, off);
    return v;
}

__device__ __forceinline__ unsigned short f2bf(float f) {   // RNE fp32 -> bf16 bits
    unsigned u = __float_as_uint(f);
    return (unsigned short)((u + 0x7fffu + ((u >> 16) & 1u)) >> 16);
}
__device__ __forceinline__ float bf2f(unsigned short h) {
    return __uint_as_float((unsigned)h << 16);
}

// ---------- fused cosine relevance + split-bf16 node features ----------
// nfs row layout along K' (2304): blocks (hi, lo, hi) of rel*nodex.
__global__ __launch_bounds__(256) void relnf_kernel(
        const float* __restrict__ text, const float* __restrict__ nodex,
        const int* __restrict__ bid, unsigned short* __restrict__ nfs) {
    int n = blockIdx.x, t = threadIdx.x;
    const float* xr = nodex + (size_t)n * HID;
    const float* tr = text + (size_t)bid[n] * HID;
    float xv[3];
    float num = 0.f, tt = 0.f, xx = 0.f;
#pragma unroll
    for (int j = 0; j < 3; j++) {
        int c = t + j * 256;
        float a = xr[c], b = tr[c];
        xv[j] = a; num += a * b; tt += b * b; xx += a * a;
    }
    num = wave_reduce_sum(num);
    tt = wave_reduce_sum(tt);
    xx = wave_reduce_sum(xx);
    __shared__ float s0[4], s1[4], s2[4];
    int lane = t & 63, wv = t >> 6;
    if (lane == 0) { s0[wv] = num; s1[wv] = tt; s2[wv] = xx; }
    __syncthreads();
    num = s0[0] + s0[1] + s0[2] + s0[3];
    tt  = s1[0] + s1[1] + s1[2] + s1[3];
    xx  = s2[0] + s2[1] + s2[2] + s2[3];
    float r = num / fmaxf(sqrtf(tt) * sqrtf(xx), 1e-8f);
    unsigned short* o = nfs + (size_t)n * 2304;
#pragma unroll
    for (int j = 0; j < 3; j++) {
        int c = t + j * 256;
        float a = xv[j] * r;
        unsigned short h = f2bf(a), l = f2bf(a - bf2f(h));
        o[c] = h; o[768 + c] = l; o[1536 + c] = h;
    }
}

// ---------- W [K,N] f32 -> out [N, 3K] bf16 (B-side block order hi,hi,lo) ----------
__global__ void wconv_kernel(const float* __restrict__ W, unsigned short* __restrict__ out,
                             int K, int N) {
    int k = blockIdx.x * 256 + threadIdx.x;
    int n = blockIdx.y;
    if (k >= K) return;
    float a = W[(size_t)k * N + n];
    unsigned short h = f2bf(a);
    unsigned short l = f2bf(a - bf2f(h));
    size_t o = (size_t)n * (3 * K);
    out[o + k] = h;
    out[o + K + k] = h;
    out[o + 2 * K + k] = l;
}

// ---------- packed per-layer weight conversion: Wall [3328, 768], ball [3328] ----------
// rows 0..1023=q, 1024..2047=k, 2048..3071=v, 3072..3327=skip
__global__ void wconv_all(const float* __restrict__ Wq, const float* __restrict__ Wk,
                          const float* __restrict__ Wv, const float* __restrict__ Ws,
                          const float* __restrict__ bq, const float* __restrict__ bk,
                          const float* __restrict__ bv, const float* __restrict__ bs,
                          unsigned short* __restrict__ Wall, float* __restrict__ ball) {
    int n = blockIdx.x, k = threadIdx.x;          // k in [0,256)
    const float* W; const float* bb; int col, ncols;
    if (n < 1024)      { W = Wq; bb = bq; col = n;        ncols = 1024; }
    else if (n < 2048) { W = Wk; bb = bk; col = n - 1024; ncols = 1024; }
    else if (n < 3072) { W = Wv; bb = bv; col = n - 2048; ncols = 1024; }
    else               { W = Ws; bb = bs; col = n - 3072; ncols = 256; }
    float a = W[(size_t)k * ncols + col];
    unsigned short h = f2bf(a), l = f2bf(a - bf2f(h));
    unsigned short* o = Wall + (size_t)n * 768;
    o[k] = h; o[256 + k] = h; o[512 + k] = l;     // hi, hi, lo
    if (k == 0) ball[n] = bb[col];
}

// ---------- XCD-chunked block swizzle (m204 bijective) ----------
__device__ __forceinline__ void swz_block(int& bx, int& by) {
    int nwg = gridDim.x * gridDim.y;
    int lin = blockIdx.y * gridDim.x + blockIdx.x;
    int qd = nwg >> 3, rr = nwg & 7;
    int xcd = lin & 7, j = lin >> 3;
    int wg = (xcd < rr ? xcd * (qd + 1) : rr * (qd + 1) + (xcd - rr) * qd) + j;
    bx = wg % gridDim.x;
    by = wg / gridDim.x;
}

// ---------- MFMA GEMM (generic): C[M,N]=A@B^T+bias; WXS: also write xs split (N==256 only)
template<bool WXS>
__global__ __launch_bounds__(256, 2) void gemm_mfma(
        const unsigned short* __restrict__ A, const unsigned short* __restrict__ B,
        const float* __restrict__ bias, float* __restrict__ C,
        unsigned short* __restrict__ xs, int N, int Kp) {
    __shared__ unsigned short As[128 * 64];
    __shared__ unsigned short Bs[128 * 64];
    int bx, by; swz_block(bx, by);
    const int tid = threadIdx.x;
    const int lane = tid & 63;
    const int wave = tid >> 6;
    const int wm = wave >> 1, wn = wave & 1;
    const int row0 = by * 128, col0 = bx * 128;
    const int l15 = lane & 15, l16 = lane >> 4;

    f32x4 acc[4][4] = {};
    const char* Ac = (const char*)A;
    const char* Bc = (const char*)B;
    const size_t rowBytes = (size_t)Kp * 2;

    for (int k0 = 0; k0 < Kp; k0 += 64) {
        __syncthreads();
#pragma unroll
        for (int i = 0; i < 4; i++) {
            int o = i * 4096 + tid * 16;
            int r = o >> 7, cb = o & 127;
            __builtin_amdgcn_global_load_lds(
                (const __attribute__((address_space(1))) void*)
                    (Ac + (size_t)(row0 + r) * rowBytes + (size_t)k0 * 2 + cb),
                (__attribute__((address_space(3))) void*)((char*)As + o), 16, 0, 0);
        }
#pragma unroll
        for (int i = 0; i < 4; i++) {
            int o = i * 4096 + tid * 16;
            int r = o >> 7, cb = o & 127;
            __builtin_amdgcn_global_load_lds(
                (const __attribute__((address_space(1))) void*)
                    (Bc + (size_t)(col0 + r) * rowBytes + (size_t)k0 * 2 + cb),
                (__attribute__((address_space(3))) void*)((char*)Bs + o), 16, 0, 0);
        }
        __syncthreads();
#pragma unroll
        for (int kk = 0; kk < 2; kk++) {
            bf16x8 af[4], bfr[4];
#pragma unroll
            for (int f = 0; f < 4; f++) {
                af[f]  = *(const bf16x8*)(As + ((wm * 64 + f * 16 + l15) * 64 + kk * 32 + l16 * 8));
                bfr[f] = *(const bf16x8*)(Bs + ((wn * 64 + f * 16 + l15) * 64 + kk * 32 + l16 * 8));
            }
#pragma unroll
            for (int fi = 0; fi < 4; fi++)
#pragma unroll
                for (int fj = 0; fj < 4; fj++)
                    acc[fi][fj] = __builtin_amdgcn_mfma_f32_16x16x32_bf16(
                        af[fi], bfr[fj], acc[fi][fj], 0, 0, 0);
        }
    }
#pragma unroll
    for (int fj = 0; fj < 4; fj++) {
        int cc = col0 + wn * 64 + fj * 16 + l15;
        float bb = bias[cc];
#pragma unroll
        for (int fi = 0; fi < 4; fi++) {
            int rbase = row0 + wm * 64 + fi * 16 + l16 * 4;
#pragma unroll
            for (int r = 0; r < 4; r++) {
                int row = rbase + r;
                float vv = acc[fi][fj][r] + bb;
                C[(size_t)row * N + cc] = vv;
                if (WXS) {      // xs row layout [hi(256) lo(256) hi(256)]
                    unsigned short h = f2bf(vv), l = f2bf(vv - bf2f(h));
                    unsigned short* xr = xs + (size_t)row * 768;
                    xr[cc] = h; xr[256 + cc] = l; xr[512 + cc] = h;
                }
            }
        }
    }
}

// ---------- fused q/k/v/skip GEMM: A[16384,768] @ Wall[3328,768]^T ----------
// epilogue routes: cols [0,1024)->qb f32, [1024,2048)->kb bf16, [2048,3072)->vb f32,
// [3072,3328)->hb f32
__global__ __launch_bounds__(256, 2) void gemm_qkvs(
        const unsigned short* __restrict__ A, const unsigned short* __restrict__ B,
        const float* __restrict__ ball, float* __restrict__ qb,
        unsigned short* __restrict__ kb, float* __restrict__ vb,
        float* __restrict__ hb, int Kp) {
    __shared__ unsigned short As[128 * 64];
    __shared__ unsigned short Bs[128 * 64];
    int bx, by; swz_block(bx, by);
    const int tid = threadIdx.x;
    const int lane = tid & 63;
    const int wave = tid >> 6;
    const int wm = wave >> 1, wn = wave & 1;
    const int row0 = by * 128, col0 = bx * 128;
    const int l15 = lane & 15, l16 = lane >> 4;

    f32x4 acc[4][4] = {};
    const char* Ac = (const char*)A;
    const char* Bc = (const char*)B;
    const size_t rowBytes = (size_t)Kp * 2;

    for (int k0 = 0; k0 < Kp; k0 += 64) {
        __syncthreads();
#pragma unroll
        for (int i = 0; i < 4; i++) {
            int o = i * 4096 + tid * 16;
            int r = o >> 7, cb = o & 127;
            __builtin_amdgcn_global_load_lds(
                (const __attribute__((address_space(1))) void*)
                    (Ac + (size_t)(row0 + r) * rowBytes + (size_t)k0 * 2 + cb),
                (__attribute__((address_space(3))) void*)((char*)As + o), 16, 0, 0);
        }
#pragma unroll
        for (int i = 0; i < 4; i++) {
            int o = i * 4096 + tid * 16;
            int r = o >> 7, cb = o & 127;
            __builtin_amdgcn_global_load_lds(
                (const __attribute__((address_space(1))) void*)
                    (Bc + (size_t)(col0 + r) * rowBytes + (size_t)k0 * 2 + cb),
                (__attribute__((address_space(3))) void*)((char*)Bs + o), 16, 0, 0);
        }
        __syncthreads();
#pragma unroll
        for (int kk = 0; kk < 2; kk++) {
            bf16x8 af[4], bfr[4];
#pragma unroll
            for (int f = 0; f < 4; f++) {
                af[f]  = *(const bf16x8*)(As + ((wm * 64 + f * 16 + l15) * 64 + kk * 32 + l16 * 8));
                bfr[f] = *(const bf16x8*)(Bs + ((wn * 64 + f * 16 + l15) * 64 + kk * 32 + l16 * 8));
            }
#pragma unroll
            for (int fi = 0; fi < 4; fi++)
#pragma unroll
                for (int fj = 0; fj < 4; fj++)
                    acc[fi][fj] = __builtin_amdgcn_mfma_f32_16x16x32_bf16(
                        af[fi], bfr[fj], acc[fi][fj], 0, 0, 0);
        }
    }
    int seg = col0 >> 10;   // block-uniform (segment bounds are multiples of 128)
#pragma unroll
    for (int fj = 0; fj < 4; fj++) {
        int cc = col0 + wn * 64 + fj * 16 + l15;
        float bb = ball[cc];
#pragma unroll
        for (int fi = 0; fi < 4; fi++) {
            int rbase = row0 + wm * 64 + fi * 16 + l16 * 4;
#pragma unroll
            for (int r = 0; r < 4; r++) {
                int row = rbase + r;
                float vv = acc[fi][fj][r] + bb;
                if (seg == 0)      qb[(size_t)row * 1024 + cc] = vv;
                else if (seg == 1) kb[(size_t)row * 1024 + (cc - 1024)] = f2bf(vv);
                else if (seg == 2) vb[(size_t)row * 1024 + (cc - 2048)] = vv;
                else               hb[(size_t)row * 256 + (cc - 3072)] = vv;
            }
        }
    }
}

// ---------- generic fp32 tiled GEMM (tiny 64x256 tp GEMM only) ----------
template<bool SCALE_A>
__global__ __launch_bounds__(256) void gemm_f32(
        const float* __restrict__ A, const float* __restrict__ B,
        const float* __restrict__ bias, const float* __restrict__ rowScale,
        float* __restrict__ C, int M, int N, int K) {
    const int BM = 64, BN = 64, BK = 16;
    __shared__ float As[BK][BM + 1];
    __shared__ float Bs[BK][BN + 1];
    int tid = threadIdx.x;
    int tx = tid & 15, ty = tid >> 4;
    int row0 = blockIdx.y * BM, col0 = blockIdx.x * BN;
    float acc[4][4] = {};
    for (int k0 = 0; k0 < K; k0 += BK) {
        {
            int c = tid & 15, r = tid >> 4;
#pragma unroll
            for (int i = 0; i < 4; i++) {
                int rr = r + 16 * i;
                float a = A[(size_t)(row0 + rr) * K + k0 + c];
                if (SCALE_A) a *= rowScale[row0 + rr];
                As[c][rr] = a;
            }
        }
        {
            int c = tid & 63, kr = tid >> 6;
#pragma unroll
            for (int i = 0; i < 4; i++) {
                int rr = kr + 4 * i;
                Bs[rr][c] = B[(size_t)(k0 + rr) * N + col0 + c];
            }
        }
        __syncthreads();
#pragma unroll
        for (int kk = 0; kk < BK; kk++) {
            float av[4], bv[4];
#pragma unroll
            for (int i = 0; i < 4; i++) av[i] = As[kk][ty * 4 + i];
#pragma unroll
            for (int j = 0; j < 4; j++) bv[j] = Bs[kk][tx * 4 + j];
#pragma unroll
            for (int i = 0; i < 4; i++)
#pragma unroll
                for (int j = 0; j < 4; j++)
                    acc[i][j] += av[i] * bv[j];
        }
        __syncthreads();
    }
#pragma unroll
    for (int i = 0; i < 4; i++) {
        int r = row0 + ty * 4 + i;
#pragma unroll
        for (int j = 0; j < 4; j++) {
            int c = col0 + tx * 4 + j;
            C[(size_t)r * N + c] = acc[i][j] + bias[c];
        }
    }
}

// ---------- CSR build ----------
__global__ void hist_kernel(const int* __restrict__ dst, int* __restrict__ cnt) {
    int e = blockIdx.x * 256 + threadIdx.x;
    if (e < N_EDGES) atomicAdd(&cnt[dst[e]], 1);
}

__global__ void scan_kernel(const int* __restrict__ cnt, int* __restrict__ base,
                            int* __restrict__ cursor) {
    int t = threadIdx.x;
    int s = 0;
    for (int i = 0; i < 64; i++) s += cnt[t * 64 + i];
    __shared__ int pref[256];
    pref[t] = s;
    __syncthreads();
    if (t == 0) {
        int a = 0;
        for (int i = 0; i < 256; i++) { int v = pref[i]; pref[i] = a; a += v; }
    }
    __syncthreads();
    int run = pref[t];
    for (int i = 0; i < 64; i++) {
        base[t * 64 + i] = run;
        cursor[t * 64 + i] = run;
        run += cnt[t * 64 + i];
    }
}

__global__ void scatter_kernel(const int* __restrict__ src, const int* __restrict__ dst,
                               int* __restrict__ cursor, int* __restrict__ esrc,
                               int* __restrict__ edst) {
    int e = blockIdx.x * 256 + threadIdx.x;
    if (e < N_EDGES) {
        int d = dst[e];
        int pos = atomicAdd(&cursor[d], 1);
        esrc[pos] = src[e];
        edst[pos] = d;
    }
}

// ---------- graph segment boundaries (batch_ids is sorted) ----------
__global__ void gbounds_kernel(const int* __restrict__ bid, int* __restrict__ gstart) {
    int g = threadIdx.x;
    if (g > N_GRAPHS) return;
    int lo = 0, hi = N_NODES;
    while (lo < hi) { int mid = (lo + hi) >> 1; if (bid[mid] < g) lo = mid + 1; else hi = mid; }
    gstart[g] = lo;
}

// ---------- edge scores at CSR positions: q fp32 · k bf16 ----------
__global__ void score_csr_kernel(const float* __restrict__ q, const unsigned short* __restrict__ kb,
                                 const int* __restrict__ esrc, const int* __restrict__ edst,
                                 float* __restrict__ sc) {
    int w = blockIdx.x * 4 + (threadIdx.x >> 6);
    int lane = threadIdx.x & 63;
    int pos = w >> 2, h = w & 3;
    int s = esrc[pos], d = edst[pos];
    float4 qa = ((const float4*)(q + (size_t)d * 1024 + h * 256))[lane];
    ushort4 ka = ((const ushort4*)(kb + (size_t)s * 1024 + h * 256))[lane];
    float p = qa.x * bf2f(ka.x) + qa.y * bf2f(ka.y) + qa.z * bf2f(ka.z) + qa.w * bf2f(ka.w);
    p = wave_reduce_sum(p);
    if (lane == 0) sc[(size_t)pos * 4 + h] = p * 0.0625f;  // 1/sqrt(256)
}

// ---------- per-node: softmax + alpha*v gather + head-mean + skip (+resid) + LN + ReLU ----------
template<bool RESID, bool WXS>
__global__ __launch_bounds__(256) void agg_norm_kernel(
        const float* __restrict__ v, const float* __restrict__ sc,
        const int* __restrict__ base, const int* __restrict__ cnt,
        const int* __restrict__ esrc, const float* __restrict__ hbuf,
        float* __restrict__ x, unsigned short* __restrict__ xs,
        const float* __restrict__ gamma, const float* __restrict__ beta) {
    __shared__ float hacc[4][256];
    __shared__ float tmp[4];
    int n = blockIdx.x;
    int tid = threadIdx.x, lane = tid & 63, h = tid >> 6;
    int start = base[n], deg = cnt[n];

    float m = -1e30f;
    for (int i = 0; i < deg; i++) m = fmaxf(m, sc[(size_t)(start + i) * 4 + h]);
    if (deg == 0) m = 0.f;
    float den = 0.f;
    for (int i = 0; i < deg; i++) den += __expf(sc[(size_t)(start + i) * 4 + h] - m);
    float inv_den = 0.25f / (den + 1e-16f);

    float4 acc = {0.f, 0.f, 0.f, 0.f};
    for (int i = 0; i < deg; i++) {
        int s = esrc[start + i];
        float a = __expf(sc[(size_t)(start + i) * 4 + h] - m) * inv_den;
        float4 vv = ((const float4*)(v + (size_t)s * 1024 + h * 256))[lane];
        acc.x += a * vv.x; acc.y += a * vv.y; acc.z += a * vv.z; acc.w += a * vv.w;
    }
    ((float4*)&hacc[h][lane * 4])[0] = acc;
    __syncthreads();

    int c = tid;
    float val = hacc[0][c] + hacc[1][c] + hacc[2][c] + hacc[3][c] + hbuf[(size_t)n * 256 + c];
    if (RESID) val += x[(size_t)n * 256 + c];

    float s1 = wave_reduce_sum(val);
    if (lane == 0) tmp[h] = s1;
    __syncthreads();
    float mu = (tmp[0] + tmp[1] + tmp[2] + tmp[3]) * (1.0f / 256.0f);
    __syncthreads();
    float d = val - mu;
    float s2 = wave_reduce_sum(d * d);
    if (lane == 0) tmp[h] = s2;
    __syncthreads();
    float inv = rsqrtf((tmp[0] + tmp[1] + tmp[2] + tmp[3]) * (1.0f / 256.0f) + 1e-5f);
    float o = fmaxf(d * inv * gamma[c] + beta[c], 0.f);
    x[(size_t)n * 256 + c] = o;
    if (WXS) {
        unsigned short hh = f2bf(o), ll = f2bf(o - bf2f(hh));
        unsigned short* xr = xs + (size_t)n * 768;
        xr[c] = hh; xr[256 + c] = ll; xr[512 + c] = hh;
    }
}

// ---------- pooling pass 1 (segmented) ----------
__global__ __launch_bounds__(256) void pool1_seg(
        const float* __restrict__ x, const float* __restrict__ tp,
        const int* __restrict__ gstart, float* __restrict__ pstruct,
        float* __restrict__ semden, float* __restrict__ semex) {
    int g = blockIdx.x >> 2, q = blockIdx.x & 3;
    int s0 = gstart[g], s1 = gstart[g + 1];
    int chunk = (s1 - s0 + 3) >> 2;
    int a = s0 + q * chunk, b = min(a + chunk, s1);
    int wave = threadIdx.x >> 6, lane = threadIdx.x & 63;
    float4 tv = ((const float4*)(tp + (size_t)g * 256))[lane];
    float4 acc = {0.f, 0.f, 0.f, 0.f};
    float esum = 0.f;
    for (int n = a + wave; n < b; n += 4) {
        float4 xv = ((const float4*)(x + (size_t)n * 256))[lane];
        float p = wave_reduce_sum(xv.x * tv.x + xv.y * tv.y + xv.z * tv.z + xv.w * tv.w);
        float e = __expf(p);
        if (lane == 0) semex[n] = e;
        esum += e;
        acc.x += xv.x; acc.y += xv.y; acc.z += xv.z; acc.w += xv.w;
    }
    __shared__ float sacc[4][256];
    __shared__ float tse[4];
    ((float4*)&sacc[wave][lane * 4])[0] = acc;
    if (lane == 0) tse[wave] = esum;
    __syncthreads();
    int c = threadIdx.x;
    float v = sacc[0][c] + sacc[1][c] + sacc[2][c] + sacc[3][c];
    atomicAdd(&pstruct[(size_t)g * 256 + c], v);
    if (threadIdx.x == 0)
        atomicAdd(&semden[g], tse[0] + tse[1] + tse[2] + tse[3]);
}

// ---------- pooling pass 2 (segmented) ----------
__global__ __launch_bounds__(256) void pool2_seg(
        const float* __restrict__ x, const int* __restrict__ gstart,
        const float* __restrict__ semden, const float* __restrict__ semex,
        float* __restrict__ psem) {
    int g = blockIdx.x >> 2, q = blockIdx.x & 3;
    int s0 = gstart[g], s1 = gstart[g + 1];
    int chunk = (s1 - s0 + 3) >> 2;
    int a = s0 + q * chunk, b = min(a + chunk, s1);
    int wave = threadIdx.x >> 6, lane = threadIdx.x & 63;
    float inv = 1.0f / (semden[g] + 1e-8f);
    float4 acc = {0.f, 0.f, 0.f, 0.f};
    for (int n = a + wave; n < b; n += 4) {
        float aw = semex[n] * inv;
        float4 xv = ((const float4*)(x + (size_t)n * 256))[lane];
        acc.x += xv.x * aw; acc.y += xv.y * aw; acc.z += xv.z * aw; acc.w += xv.w * aw;
    }
    __shared__ float sacc[4][256];
    ((float4*)&sacc[wave][lane * 4])[0] = acc;
    __syncthreads();
    int c = threadIdx.x;
    float v = sacc[0][c] + sacc[1][c] + sacc[2][c] + sacc[3][c];
    atomicAdd(&psem[(size_t)g * 256 + c], v);
}

// ---------- classifier ----------
__global__ void clf_kernel(const float* __restrict__ pstruct, const float* __restrict__ psem,
                           const int* __restrict__ gstart, const float* __restrict__ text,
                           const float* __restrict__ w, const float* __restrict__ b,
                           float* __restrict__ out) {
    int g = blockIdx.x * 4 + (threadIdx.x >> 6);
    int lane = threadIdx.x & 63;
    float invc = 1.0f / fmaxf((float)(gstart[g + 1] - gstart[g]), 1.0f);
    float acc = 0.f;
#pragma unroll
    for (int i = 0; i < 4; i++) { int c = lane + i * 64; acc += pstruct[(size_t)g * 256 + c] * invc * w[c]; }
#pragma unroll
    for (int i = 0; i < 4; i++) { int c = lane + i * 64; acc += psem[(size_t)g * 256 + c] * w[256 + c]; }
#pragma unroll
    for (int i = 0; i < 12; i++) { int c = lane + i * 64; acc += text[(size_t)g * 768 + c] * w[512 + c]; }
    acc = wave_reduce_sum(acc);
    if (lane == 0) out[g] = acc + b[0];
}

extern "C" void kernel_launch(void* const* d_in, const int* in_sizes, int n_in,
                              void* d_out, int out_size, void* d_ws, size_t ws_size,
                              hipStream_t stream) {
    const float* text  = (const float*)d_in[0];
    const float* nodex = (const float*)d_in[1];
    const float* Wp    = (const float*)d_in[2];
    const float* bp    = (const float*)d_in[3];
    const float* Wq    = (const float*)d_in[4];
    const float* bq    = (const float*)d_in[5];
    const float* Wk    = (const float*)d_in[6];
    const float* bk    = (const float*)d_in[7];
    const float* Wv    = (const float*)d_in[8];
    const float* bv    = (const float*)d_in[9];
    const float* Ws    = (const float*)d_in[10];
    const float* bs    = (const float*)d_in[11];
    const float* gamma = (const float*)d_in[12];
    const float* beta  = (const float*)d_in[13];
    const float* clfw  = (const float*)d_in[14];
    const float* clfb  = (const float*)d_in[15];
    const int*   eidx  = (const int*)d_in[16];
    const int*   bid   = (const int*)d_in[17];
    const int* src = eidx;
    const int* dst = eidx + N_EDGES;
    float* out = (float*)d_out;

    // workspace layout (16B-aligned segments)
    float* x     = (float*)d_ws;                     // 16384*256
    float* hbuf  = x + (size_t)N_NODES * 256;        // 16384*256
    float* qbuf  = hbuf + (size_t)N_NODES * 256;     // 16384*1024 f32
    float* vbuf  = qbuf + (size_t)N_NODES * 1024;    // 16384*1024 f32
    float* tp64  = vbuf + (size_t)N_NODES * 1024;    // 64*256
    float* sc    = tp64 + 64 * 256;                  // 65536*4
    float* semex = sc + (size_t)N_EDGES * 4;         // 16384
    float* pstruct = semex + N_NODES;                // 64*256
    float* psem  = pstruct + 64 * 256;               // 64*256
    float* semden = psem + 64 * 256;                 // 64
    float* ball  = semden + 64;                      // 3328
    int* esrc    = (int*)(ball + 3328);              // 65536
    int* edst    = esrc + N_EDGES;                   // 65536
    int* cnt     = edst + N_EDGES;                   // 16384
    int* base    = cnt + N_NODES;                    // 16384
    int* cursor  = base + N_NODES;                   // 16384
    int* gstart  = cursor + N_NODES;                 // 80 (65 used)
    unsigned short* kb  = (unsigned short*)(gstart + 80);   // 16384*1024 bf16
    unsigned short* xs  = kb + (size_t)N_NODES * 1024;      // 16384*768
    unsigned short* Wall = xs + (size_t)N_NODES * 768;      // 3328*768
    unsigned short* Wps = Wall + (size_t)3328 * 768;        // 256*2304
    // nfs [16384, 2304] aliases qbuf+vbuf (consumed by proj GEMM before those are written)
    unsigned short* nfs = (unsigned short*)qbuf;

    // relevance + split node features (fused), CSR build, graph bounds
    relnf_kernel<<<N_NODES, 256, 0, stream>>>(text, nodex, bid, nfs);
    hipMemsetAsync(cnt, 0, N_NODES * sizeof(int), stream);
    hist_kernel<<<N_EDGES / 256, 256, 0, stream>>>(dst, cnt);
    scan_kernel<<<1, 256, 0, stream>>>(cnt, base, cursor);
    scatter_kernel<<<N_EDGES / 256, 256, 0, stream>>>(src, dst, cursor, esrc, edst);
    gbounds_kernel<<<1, 128, 0, stream>>>(bid, gstart);

    // projection: x = (diag(rel)*nodex) @ Wp + bp, also emits xs = split(x)
    wconv_kernel<<<dim3(HID / 256, DDIM), 256, 0, stream>>>(Wp, Wps, HID, DDIM);
    gemm_mfma<true><<<dim3(DDIM / 128, N_NODES / 128), 256, 0, stream>>>(
        nfs, Wps, bp, x, xs, DDIM, 3 * HID);
    // tiny text projection stays fp32
    gemm_f32<false><<<dim3(DDIM / 64, 1), 256, 0, stream>>>(
        text, Wp, bp, nullptr, tp64, N_GRAPHS, DDIM, HID);

    for (int i = 0; i < 2; i++) {
        // packed weight conversion (q|k|v|skip -> Wall, biases -> ball)
        wconv_all<<<3328, 256, 0, stream>>>(
            Wq + (size_t)i * DDIM * 1024, Wk + (size_t)i * DDIM * 1024,
            Wv + (size_t)i * DDIM * 1024, Ws + (size_t)i * DDIM * DDIM,
            bq + i * 1024, bk + i * 1024, bv + i * 1024, bs + i * DDIM,
            Wall, ball);
        // fused q/k/v/skip GEMM (q,v,skip fp32; k bf16)
        gemm_qkvs<<<dim3(3328 / 128, N_NODES / 128), 256, 0, stream>>>(
            xs, Wall, ball, qbuf, kb, vbuf, hbuf, 768);
        // scores at CSR positions
        score_csr_kernel<<<N_EDGES, 256, 0, stream>>>(qbuf, kb, esrc, edst, sc);
        // softmax + gather + head-mean + skip + (resid) + LN + ReLU (+xs for next layer)
        if (i == 0)
            agg_norm_kernel<true, true><<<N_NODES, 256, 0, stream>>>(
                vbuf, sc, base, cnt, esrc, hbuf, x, xs, gamma, beta);
        else
            agg_norm_kernel<false, false><<<N_NODES, 256, 0, stream>>>(
                vbuf, sc, base, cnt, esrc, hbuf, x, nullptr, gamma + 256, beta + 256);
    }

    // pools (pstruct, psem, semden contiguous)
    hipMemsetAsync(pstruct, 0, (size_t)(64 * 256 * 2 + 64) * sizeof(float), stream);
    pool1_seg<<<N_GRAPHS * 4, 256, 0, stream>>>(x, tp64, gstart, pstruct, semden, semex);
    pool2_seg<<<N_GRAPHS * 4, 256, 0, stream>>>(x, gstart, semden, semex, psem);
    clf_kernel<<<N_GRAPHS / 4, 256, 0, stream>>>(pstruct, psem, gstart, text, clfw, clfb, out);
}

// Round 4
// 610.824 us; speedup vs baseline: 2.9774x; 1.2231x over previous
//
#include <hip/hip_runtime.h>

#define N_NODES 16384
#define N_EDGES 65536
#define N_GRAPHS 64
#define HID 768
#define DDIM 256
#define HEADS 4

typedef __attribute__((ext_vector_type(8))) short bf16x8;   // 8 bf16 = 4 VGPR (MFMA A/B frag)
typedef __attribute__((ext_vector_type(4))) float f32x4;    // MFMA C/D frag
typedef __attribute__((ext_vector_type(8))) unsigned short u16x8;

// ---------- helpers ----------
__device__ __forceinline__ float wave_reduce_sum(float v) {
#pragma unroll
    for (int off = 32; off; off >>= 1) v += __shfl_xor(v, off);
    return v;
}

__device__ __forceinline__ unsigned short f2bf(float f) {   // RNE fp32 -> bf16 bits
    unsigned u = __float_as_uint(f);
    return (unsigned short)((u + 0x7fffu + ((u >> 16) & 1u)) >> 16);
}
__device__ __forceinline__ float bf2f(unsigned short h) {
    return __uint_as_float((unsigned)h << 16);
}

// ---------- fused cosine relevance + split-bf16 node features ----------
// nfs row layout along K' (2304): blocks (hi, lo, hi) of rel*nodex.
__global__ __launch_bounds__(256) void relnf_kernel(
        const float* __restrict__ text, const float* __restrict__ nodex,
        const int* __restrict__ bid, unsigned short* __restrict__ nfs) {
    int n = blockIdx.x, t = threadIdx.x;
    const float* xr = nodex + (size_t)n * HID;
    const float* tr = text + (size_t)bid[n] * HID;
    float xv[3];
    float num = 0.f, tt = 0.f, xx = 0.f;
#pragma unroll
    for (int j = 0; j < 3; j++) {
        int c = t + j * 256;
        float a = xr[c], b = tr[c];
        xv[j] = a; num += a * b; tt += b * b; xx += a * a;
    }
    num = wave_reduce_sum(num);
    tt = wave_reduce_sum(tt);
    xx = wave_reduce_sum(xx);
    __shared__ float s0[4], s1[4], s2[4];
    int lane = t & 63, wv = t >> 6;
    if (lane == 0) { s0[wv] = num; s1[wv] = tt; s2[wv] = xx; }
    __syncthreads();
    num = s0[0] + s0[1] + s0[2] + s0[3];
    tt  = s1[0] + s1[1] + s1[2] + s1[3];
    xx  = s2[0] + s2[1] + s2[2] + s2[3];
    float r = num / fmaxf(sqrtf(tt) * sqrtf(xx), 1e-8f);
    unsigned short* o = nfs + (size_t)n * 2304;
#pragma unroll
    for (int j = 0; j < 3; j++) {
        int c = t + j * 256;
        float a = xv[j] * r;
        unsigned short h = f2bf(a), l = f2bf(a - bf2f(h));
        o[c] = h; o[768 + c] = l; o[1536 + c] = h;
    }
}

// ---------- W [K,N] f32 -> out [N, 3K] bf16 (B-side block order hi,hi,lo) ----------
__global__ void wconv_kernel(const float* __restrict__ W, unsigned short* __restrict__ out,
                             int K, int N) {
    int k = blockIdx.x * 256 + threadIdx.x;
    int n = blockIdx.y;
    if (k >= K) return;
    float a = W[(size_t)k * N + n];
    unsigned short h = f2bf(a);
    unsigned short l = f2bf(a - bf2f(h));
    size_t o = (size_t)n * (3 * K);
    out[o + k] = h;
    out[o + K + k] = h;
    out[o + 2 * K + k] = l;
}

// ---------- per-layer weights: Wqkv [3072,256] bf16 1-term; Wsk [256,768] 3-term ----------
// ball[0..3071] = q|k|v biases, ball[3072..3327] = skip bias
__global__ void wconv_layer(const float* __restrict__ Wq, const float* __restrict__ Wk,
                            const float* __restrict__ Wv, const float* __restrict__ Ws,
                            const float* __restrict__ bq, const float* __restrict__ bk,
                            const float* __restrict__ bv, const float* __restrict__ bs,
                            unsigned short* __restrict__ Wqkv,
                            unsigned short* __restrict__ Wsk, float* __restrict__ ball) {
    int n = blockIdx.x, k = threadIdx.x;          // k in [0,256)
    if (n < 3072) {
        const float* W; const float* bb; int col;
        if (n < 1024)      { W = Wq; bb = bq; col = n; }
        else if (n < 2048) { W = Wk; bb = bk; col = n - 1024; }
        else               { W = Wv; bb = bv; col = n - 2048; }
        Wqkv[(size_t)n * 256 + k] = f2bf(W[(size_t)k * 1024 + col]);
        if (k == 0) ball[n] = bb[col];
    } else {
        int col = n - 3072;
        float a = Ws[(size_t)k * 256 + col];
        unsigned short h = f2bf(a), l = f2bf(a - bf2f(h));
        unsigned short* o = Wsk + (size_t)col * 768;
        o[k] = h; o[256 + k] = h; o[512 + k] = l;
        if (k == 0) ball[n] = bs[col];
    }
}

// ---------- XCD-chunked block swizzle (m204 bijective) ----------
__device__ __forceinline__ void swz_block(int& bx, int& by) {
    int nwg = gridDim.x * gridDim.y;
    int lin = blockIdx.y * gridDim.x + blockIdx.x;
    int qd = nwg >> 3, rr = nwg & 7;
    int xcd = lin & 7, j = lin >> 3;
    int wg = (xcd < rr ? xcd * (qd + 1) : rr * (qd + 1) + (xcd - rr) * qd) + j;
    bx = wg % gridDim.x;
    by = wg / gridDim.x;
}

// ---------- MFMA GEMM (generic fp32-out): C[M,N]=A@B^T+bias; WXS: also write xs split ----------
template<bool WXS>
__global__ __launch_bounds__(256, 2) void gemm_mfma(
        const unsigned short* __restrict__ A, const unsigned short* __restrict__ B,
        const float* __restrict__ bias, float* __restrict__ C,
        unsigned short* __restrict__ xs, int N, int Kp) {
    __shared__ unsigned short As[128 * 64];
    __shared__ unsigned short Bs[128 * 64];
    int bx, by; swz_block(bx, by);
    const int tid = threadIdx.x;
    const int lane = tid & 63;
    const int wave = tid >> 6;
    const int wm = wave >> 1, wn = wave & 1;
    const int row0 = by * 128, col0 = bx * 128;
    const int l15 = lane & 15, l16 = lane >> 4;

    f32x4 acc[4][4] = {};
    const char* Ac = (const char*)A;
    const char* Bc = (const char*)B;
    const size_t rowBytes = (size_t)Kp * 2;

    for (int k0 = 0; k0 < Kp; k0 += 64) {
        __syncthreads();
#pragma unroll
        for (int i = 0; i < 4; i++) {
            int o = i * 4096 + tid * 16;
            int r = o >> 7, cb = o & 127;
            __builtin_amdgcn_global_load_lds(
                (const __attribute__((address_space(1))) void*)
                    (Ac + (size_t)(row0 + r) * rowBytes + (size_t)k0 * 2 + cb),
                (__attribute__((address_space(3))) void*)((char*)As + o), 16, 0, 0);
        }
#pragma unroll
        for (int i = 0; i < 4; i++) {
            int o = i * 4096 + tid * 16;
            int r = o >> 7, cb = o & 127;
            __builtin_amdgcn_global_load_lds(
                (const __attribute__((address_space(1))) void*)
                    (Bc + (size_t)(col0 + r) * rowBytes + (size_t)k0 * 2 + cb),
                (__attribute__((address_space(3))) void*)((char*)Bs + o), 16, 0, 0);
        }
        __syncthreads();
#pragma unroll
        for (int kk = 0; kk < 2; kk++) {
            bf16x8 af[4], bfr[4];
#pragma unroll
            for (int f = 0; f < 4; f++) {
                af[f]  = *(const bf16x8*)(As + ((wm * 64 + f * 16 + l15) * 64 + kk * 32 + l16 * 8));
                bfr[f] = *(const bf16x8*)(Bs + ((wn * 64 + f * 16 + l15) * 64 + kk * 32 + l16 * 8));
            }
#pragma unroll
            for (int fi = 0; fi < 4; fi++)
#pragma unroll
                for (int fj = 0; fj < 4; fj++)
                    acc[fi][fj] = __builtin_amdgcn_mfma_f32_16x16x32_bf16(
                        af[fi], bfr[fj], acc[fi][fj], 0, 0, 0);
        }
    }
#pragma unroll
    for (int fj = 0; fj < 4; fj++) {
        int cc = col0 + wn * 64 + fj * 16 + l15;
        float bb = bias[cc];
#pragma unroll
        for (int fi = 0; fi < 4; fi++) {
            int rbase = row0 + wm * 64 + fi * 16 + l16 * 4;
#pragma unroll
            for (int r = 0; r < 4; r++) {
                int row = rbase + r;
                float vv = acc[fi][fj][r] + bb;
                C[(size_t)row * N + cc] = vv;
                if (WXS) {      // xs row layout [hi(256) lo(256) hi(256)]
                    unsigned short h = f2bf(vv), l = f2bf(vv - bf2f(h));
                    unsigned short* xr = xs + (size_t)row * 768;
                    xr[cc] = h; xr[256 + cc] = l; xr[512 + cc] = h;
                }
            }
        }
    }
}

// ---------- 1-term bf16 qkv GEMM: [16384,3072] = xs_hi[16384,256] @ Wqkv^T ----------
// outputs q/k/v bf16 via LDS-staged coalesced stores (no write amplification)
__global__ __launch_bounds__(256, 2) void gemm_qkv(
        const unsigned short* __restrict__ A,   // xs [16384,768]; hi block = cols 0..255
        const unsigned short* __restrict__ B,   // Wqkv [3072,256]
        const float* __restrict__ ball,
        unsigned short* __restrict__ qb, unsigned short* __restrict__ kb,
        unsigned short* __restrict__ vb) {
    __shared__ unsigned short smem[128 * 128];  // As | Bs during K-loop, C-tile after
    unsigned short* As = smem;
    unsigned short* Bs = smem + 128 * 64;
    int bx, by; swz_block(bx, by);
    const int tid = threadIdx.x;
    const int lane = tid & 63;
    const int wave = tid >> 6;
    const int wm = wave >> 1, wn = wave & 1;
    const int row0 = by * 128, col0 = bx * 128;
    const int l15 = lane & 15, l16 = lane >> 4;

    f32x4 acc[4][4] = {};
    const char* Ac = (const char*)A;
    const char* Bc = (const char*)B;

    for (int k0 = 0; k0 < 256; k0 += 64) {
        __syncthreads();
#pragma unroll
        for (int i = 0; i < 4; i++) {           // A: rows stride 1536B, hi block only
            int o = i * 4096 + tid * 16;
            int r = o >> 7, cb = o & 127;
            __builtin_amdgcn_global_load_lds(
                (const __attribute__((address_space(1))) void*)
                    (Ac + (size_t)(row0 + r) * 1536 + k0 * 2 + cb),
                (__attribute__((address_space(3))) void*)((char*)As + o), 16, 0, 0);
        }
#pragma unroll
        for (int i = 0; i < 4; i++) {           // B: rows stride 512B
            int o = i * 4096 + tid * 16;
            int r = o >> 7, cb = o & 127;
            __builtin_amdgcn_global_load_lds(
                (const __attribute__((address_space(1))) void*)
                    (Bc + (size_t)(col0 + r) * 512 + k0 * 2 + cb),
                (__attribute__((address_space(3))) void*)((char*)Bs + o), 16, 0, 0);
        }
        __syncthreads();
#pragma unroll
        for (int kk = 0; kk < 2; kk++) {
            bf16x8 af[4], bfr[4];
#pragma unroll
            for (int f = 0; f < 4; f++) {
                af[f]  = *(const bf16x8*)(As + ((wm * 64 + f * 16 + l15) * 64 + kk * 32 + l16 * 8));
                bfr[f] = *(const bf16x8*)(Bs + ((wn * 64 + f * 16 + l15) * 64 + kk * 32 + l16 * 8));
            }
#pragma unroll
            for (int fi = 0; fi < 4; fi++)
#pragma unroll
                for (int fj = 0; fj < 4; fj++)
                    acc[fi][fj] = __builtin_amdgcn_mfma_f32_16x16x32_bf16(
                        af[fi], bfr[fj], acc[fi][fj], 0, 0, 0);
        }
    }
    __syncthreads();                // all waves done reading As/Bs; reuse as C-stage
    // stage bf16 C-tile to LDS with 16B-chunk row-XOR swizzle
#pragma unroll
    for (int fj = 0; fj < 4; fj++) {
        int cl = wn * 64 + fj * 16 + l15;       // local col 0..127
        float bb = ball[col0 + cl];
#pragma unroll
        for (int fi = 0; fi < 4; fi++) {
#pragma unroll
            for (int r = 0; r < 4; r++) {
                int rl = wm * 64 + fi * 16 + l16 * 4 + r;   // local row 0..127
                int chunk = (cl >> 3) ^ (rl & 15);
                smem[rl * 128 + chunk * 8 + (cl & 7)] = f2bf(acc[fi][fj][r] + bb);
            }
        }
    }
    __syncthreads();
    // coalesced store: thread writes 128B contiguous of one row
    int seg = col0 >> 10;           // 0=q, 1=k, 2=v (block-uniform)
    unsigned short* dstp = seg == 0 ? qb : (seg == 1 ? kb : vb);
    int rl = tid >> 1, half = tid & 1;
    dstp += (size_t)(row0 + rl) * 1024 + (col0 & 1023) + half * 64;
#pragma unroll
    for (int i = 0; i < 8; i++) {
        int chunk = (half * 8 + i) ^ (rl & 15);
        ((u16x8*)dstp)[i] = *(const u16x8*)(smem + rl * 128 + chunk * 8);
    }
}

// ---------- generic fp32 tiled GEMM (tiny 64x256 tp GEMM only) ----------
template<bool SCALE_A>
__global__ __launch_bounds__(256) void gemm_f32(
        const float* __restrict__ A, const float* __restrict__ B,
        const float* __restrict__ bias, const float* __restrict__ rowScale,
        float* __restrict__ C, int M, int N, int K) {
    const int BM = 64, BN = 64, BK = 16;
    __shared__ float As[BK][BM + 1];
    __shared__ float Bs[BK][BN + 1];
    int tid = threadIdx.x;
    int tx = tid & 15, ty = tid >> 4;
    int row0 = blockIdx.y * BM, col0 = blockIdx.x * BN;
    float acc[4][4] = {};
    for (int k0 = 0; k0 < K; k0 += BK) {
        {
            int c = tid & 15, r = tid >> 4;
#pragma unroll
            for (int i = 0; i < 4; i++) {
                int rr = r + 16 * i;
                float a = A[(size_t)(row0 + rr) * K + k0 + c];
                if (SCALE_A) a *= rowScale[row0 + rr];
                As[c][rr] = a;
            }
        }
        {
            int c = tid & 63, kr = tid >> 6;
#pragma unroll
            for (int i = 0; i < 4; i++) {
                int rr = kr + 4 * i;
                Bs[rr][c] = B[(size_t)(k0 + rr) * N + col0 + c];
            }
        }
        __syncthreads();
#pragma unroll
        for (int kk = 0; kk < BK; kk++) {
            float av[4], bv[4];
#pragma unroll
            for (int i = 0; i < 4; i++) av[i] = As[kk][ty * 4 + i];
#pragma unroll
            for (int j = 0; j < 4; j++) bv[j] = Bs[kk][tx * 4 + j];
#pragma unroll
            for (int i = 0; i < 4; i++)
#pragma unroll
                for (int j = 0; j < 4; j++)
                    acc[i][j] += av[i] * bv[j];
        }
        __syncthreads();
    }
#pragma unroll
    for (int i = 0; i < 4; i++) {
        int r = row0 + ty * 4 + i;
#pragma unroll
        for (int j = 0; j < 4; j++) {
            int c = col0 + tx * 4 + j;
            C[(size_t)r * N + c] = acc[i][j] + bias[c];
        }
    }
}

// ---------- CSR build ----------
__global__ void hist_kernel(const int* __restrict__ dst, int* __restrict__ cnt) {
    int e = blockIdx.x * 256 + threadIdx.x;
    if (e < N_EDGES) atomicAdd(&cnt[dst[e]], 1);
}

__global__ void scan_kernel(const int* __restrict__ cnt, int* __restrict__ base,
                            int* __restrict__ cursor) {
    int t = threadIdx.x;
    int s = 0;
    for (int i = 0; i < 64; i++) s += cnt[t * 64 + i];
    __shared__ int pref[256];
    pref[t] = s;
    __syncthreads();
    if (t == 0) {
        int a = 0;
        for (int i = 0; i < 256; i++) { int v = pref[i]; pref[i] = a; a += v; }
    }
    __syncthreads();
    int run = pref[t];
    for (int i = 0; i < 64; i++) {
        base[t * 64 + i] = run;
        cursor[t * 64 + i] = run;
        run += cnt[t * 64 + i];
    }
}

__global__ void scatter_kernel(const int* __restrict__ src, const int* __restrict__ dst,
                               int* __restrict__ cursor, int* __restrict__ esrc,
                               int* __restrict__ edst) {
    int e = blockIdx.x * 256 + threadIdx.x;
    if (e < N_EDGES) {
        int d = dst[e];
        int pos = atomicAdd(&cursor[d], 1);
        esrc[pos] = src[e];
        edst[pos] = d;
    }
}

// ---------- graph segment boundaries (batch_ids is sorted) ----------
__global__ void gbounds_kernel(const int* __restrict__ bid, int* __restrict__ gstart) {
    int g = threadIdx.x;
    if (g > N_GRAPHS) return;
    int lo = 0, hi = N_NODES;
    while (lo < hi) { int mid = (lo + hi) >> 1; if (bid[mid] < g) lo = mid + 1; else hi = mid; }
    gstart[g] = lo;
}

// ---------- edge scores at CSR positions: q bf16 · k bf16 ----------
__global__ void score_csr_kernel(const unsigned short* __restrict__ qb,
                                 const unsigned short* __restrict__ kb,
                                 const int* __restrict__ esrc, const int* __restrict__ edst,
                                 float* __restrict__ sc) {
    int w = blockIdx.x * 4 + (threadIdx.x >> 6);
    int lane = threadIdx.x & 63;
    int pos = w >> 2, h = w & 3;
    int s = esrc[pos], d = edst[pos];
    ushort4 qa = ((const ushort4*)(qb + (size_t)d * 1024 + h * 256))[lane];
    ushort4 ka = ((const ushort4*)(kb + (size_t)s * 1024 + h * 256))[lane];
    float p = bf2f(qa.x) * bf2f(ka.x) + bf2f(qa.y) * bf2f(ka.y)
            + bf2f(qa.z) * bf2f(ka.z) + bf2f(qa.w) * bf2f(ka.w);
    p = wave_reduce_sum(p);
    if (lane == 0) sc[(size_t)pos * 4 + h] = p * 0.0625f;  // 1/sqrt(256)
}

// ---------- per-node: softmax + alpha*v gather (v bf16) + head-mean + skip (+resid) + LN + ReLU ----------
template<bool RESID, bool WXS>
__global__ __launch_bounds__(256) void agg_norm_kernel(
        const unsigned short* __restrict__ vb, const float* __restrict__ sc,
        const int* __restrict__ base, const int* __restrict__ cnt,
        const int* __restrict__ esrc, const float* __restrict__ hbuf,
        float* __restrict__ x, unsigned short* __restrict__ xs,
        const float* __restrict__ gamma, const float* __restrict__ beta) {
    __shared__ float hacc[4][256];
    __shared__ float tmp[4];
    int n = blockIdx.x;
    int tid = threadIdx.x, lane = tid & 63, h = tid >> 6;
    int start = base[n], deg = cnt[n];

    float m = -1e30f;
    for (int i = 0; i < deg; i++) m = fmaxf(m, sc[(size_t)(start + i) * 4 + h]);
    if (deg == 0) m = 0.f;
    float den = 0.f;
    for (int i = 0; i < deg; i++) den += __expf(sc[(size_t)(start + i) * 4 + h] - m);
    float inv_den = 0.25f / (den + 1e-16f);

    float4 acc = {0.f, 0.f, 0.f, 0.f};
    for (int i = 0; i < deg; i++) {
        int s = esrc[start + i];
        float a = __expf(sc[(size_t)(start + i) * 4 + h] - m) * inv_den;
        ushort4 vv = ((const ushort4*)(vb + (size_t)s * 1024 + h * 256))[lane];
        acc.x += a * bf2f(vv.x); acc.y += a * bf2f(vv.y);
        acc.z += a * bf2f(vv.z); acc.w += a * bf2f(vv.w);
    }
    ((float4*)&hacc[h][lane * 4])[0] = acc;
    __syncthreads();

    int c = tid;
    float val = hacc[0][c] + hacc[1][c] + hacc[2][c] + hacc[3][c] + hbuf[(size_t)n * 256 + c];
    if (RESID) val += x[(size_t)n * 256 + c];

    float s1 = wave_reduce_sum(val);
    if (lane == 0) tmp[h] = s1;
    __syncthreads();
    float mu = (tmp[0] + tmp[1] + tmp[2] + tmp[3]) * (1.0f / 256.0f);
    __syncthreads();
    float d = val - mu;
    float s2 = wave_reduce_sum(d * d);
    if (lane == 0) tmp[h] = s2;
    __syncthreads();
    float inv = rsqrtf((tmp[0] + tmp[1] + tmp[2] + tmp[3]) * (1.0f / 256.0f) + 1e-5f);
    float o = fmaxf(d * inv * gamma[c] + beta[c], 0.f);
    x[(size_t)n * 256 + c] = o;
    if (WXS) {
        unsigned short hh = f2bf(o), ll = f2bf(o - bf2f(hh));
        unsigned short* xr = xs + (size_t)n * 768;
        xr[c] = hh; xr[256 + c] = ll; xr[512 + c] = hh;
    }
}

// ---------- pooling pass 1 (segmented) ----------
__global__ __launch_bounds__(256) void pool1_seg(
        const float* __restrict__ x, const float* __restrict__ tp,
        const int* __restrict__ gstart, float* __restrict__ pstruct,
        float* __restrict__ semden, float* __restrict__ semex) {
    int g = blockIdx.x >> 2, q = blockIdx.x & 3;
    int s0 = gstart[g], s1 = gstart[g + 1];
    int chunk = (s1 - s0 + 3) >> 2;
    int a = s0 + q * chunk, b = min(a + chunk, s1);
    int wave = threadIdx.x >> 6, lane = threadIdx.x & 63;
    float4 tv = ((const float4*)(tp + (size_t)g * 256))[lane];
    float4 acc = {0.f, 0.f, 0.f, 0.f};
    float esum = 0.f;
    for (int n = a + wave; n < b; n += 4) {
        float4 xv = ((const float4*)(x + (size_t)n * 256))[lane];
        float p = wave_reduce_sum(xv.x * tv.x + xv.y * tv.y + xv.z * tv.z + xv.w * tv.w);
        float e = __expf(p);
        if (lane == 0) semex[n] = e;
        esum += e;
        acc.x += xv.x; acc.y += xv.y; acc.z += xv.z; acc.w += xv.w;
    }
    __shared__ float sacc[4][256];
    __shared__ float tse[4];
    ((float4*)&sacc[wave][lane * 4])[0] = acc;
    if (lane == 0) tse[wave] = esum;
    __syncthreads();
    int c = threadIdx.x;
    float v = sacc[0][c] + sacc[1][c] + sacc[2][c] + sacc[3][c];
    atomicAdd(&pstruct[(size_t)g * 256 + c], v);
    if (threadIdx.x == 0)
        atomicAdd(&semden[g], tse[0] + tse[1] + tse[2] + tse[3]);
}

// ---------- pooling pass 2 (segmented) ----------
__global__ __launch_bounds__(256) void pool2_seg(
        const float* __restrict__ x, const int* __restrict__ gstart,
        const float* __restrict__ semden, const float* __restrict__ semex,
        float* __restrict__ psem) {
    int g = blockIdx.x >> 2, q = blockIdx.x & 3;
    int s0 = gstart[g], s1 = gstart[g + 1];
    int chunk = (s1 - s0 + 3) >> 2;
    int a = s0 + q * chunk, b = min(a + chunk, s1);
    int wave = threadIdx.x >> 6, lane = threadIdx.x & 63;
    float inv = 1.0f / (semden[g] + 1e-8f);
    float4 acc = {0.f, 0.f, 0.f, 0.f};
    for (int n = a + wave; n < b; n += 4) {
        float aw = semex[n] * inv;
        float4 xv = ((const float4*)(x + (size_t)n * 256))[lane];
        acc.x += xv.x * aw; acc.y += xv.y * aw; acc.z += xv.z * aw; acc.w += xv.w * aw;
    }
    __shared__ float sacc[4][256];
    ((float4*)&sacc[wave][lane * 4])[0] = acc;
    __syncthreads();
    int c = threadIdx.x;
    float v = sacc[0][c] + sacc[1][c] + sacc[2][c] + sacc[3][c];
    atomicAdd(&psem[(size_t)g * 256 + c], v);
}

// ---------- classifier ----------
__global__ void clf_kernel(const float* __restrict__ pstruct, const float* __restrict__ psem,
                           const int* __restrict__ gstart, const float* __restrict__ text,
                           const float* __restrict__ w, const float* __restrict__ b,
                           float* __restrict__ out) {
    int g = blockIdx.x * 4 + (threadIdx.x >> 6);
    int lane = threadIdx.x & 63;
    float invc = 1.0f / fmaxf((float)(gstart[g + 1] - gstart[g]), 1.0f);
    float acc = 0.f;
#pragma unroll
    for (int i = 0; i < 4; i++) { int c = lane + i * 64; acc += pstruct[(size_t)g * 256 + c] * invc * w[c]; }
#pragma unroll
    for (int i = 0; i < 4; i++) { int c = lane + i * 64; acc += psem[(size_t)g * 256 + c] * w[256 + c]; }
#pragma unroll
    for (int i = 0; i < 12; i++) { int c = lane + i * 64; acc += text[(size_t)g * 768 + c] * w[512 + c]; }
    acc = wave_reduce_sum(acc);
    if (lane == 0) out[g] = acc + b[0];
}

extern "C" void kernel_launch(void* const* d_in, const int* in_sizes, int n_in,
                              void* d_out, int out_size, void* d_ws, size_t ws_size,
                              hipStream_t stream) {
    const float* text  = (const float*)d_in[0];
    const float* nodex = (const float*)d_in[1];
    const float* Wp    = (const float*)d_in[2];
    const float* bp    = (const float*)d_in[3];
    const float* Wq    = (const float*)d_in[4];
    const float* bq    = (const float*)d_in[5];
    const float* Wk    = (const float*)d_in[6];
    const float* bk    = (const float*)d_in[7];
    const float* Wv    = (const float*)d_in[8];
    const float* bv    = (const float*)d_in[9];
    const float* Ws    = (const float*)d_in[10];
    const float* bs    = (const float*)d_in[11];
    const float* gamma = (const float*)d_in[12];
    const float* beta  = (const float*)d_in[13];
    const float* clfw  = (const float*)d_in[14];
    const float* clfb  = (const float*)d_in[15];
    const int*   eidx  = (const int*)d_in[16];
    const int*   bid   = (const int*)d_in[17];
    const int* src = eidx;
    const int* dst = eidx + N_EDGES;
    float* out = (float*)d_out;

    // workspace layout
    float* x     = (float*)d_ws;                     // 16384*256 f32
    float* hbuf  = x + (size_t)N_NODES * 256;        // 16384*256
    float* tp64  = hbuf + (size_t)N_NODES * 256;     // 64*256
    float* sc    = tp64 + 64 * 256;                  // 65536*4
    float* semex = sc + (size_t)N_EDGES * 4;         // 16384
    float* pstruct = semex + N_NODES;                // 64*256
    float* psem  = pstruct + 64 * 256;               // 64*256
    float* semden = psem + 64 * 256;                 // 64
    float* ball  = semden + 64;                      // 3328
    int* esrc    = (int*)(ball + 3328);              // 65536
    int* edst    = esrc + N_EDGES;                   // 65536
    int* cnt     = edst + N_EDGES;                   // 16384
    int* base    = cnt + N_NODES;                    // 16384
    int* cursor  = base + N_NODES;                   // 16384
    int* gstart  = cursor + N_NODES;                 // 80 (65 used)
    unsigned short* qb   = (unsigned short*)(gstart + 80);  // 16384*1024 bf16
    unsigned short* kb   = qb + (size_t)N_NODES * 1024;     // 16384*1024
    unsigned short* vb   = kb + (size_t)N_NODES * 1024;     // 16384*1024
    unsigned short* xs   = vb + (size_t)N_NODES * 1024;     // 16384*768
    unsigned short* Wqkv = xs + (size_t)N_NODES * 768;      // 3072*256
    unsigned short* Wsk  = Wqkv + (size_t)3072 * 256;       // 256*768
    unsigned short* Wps  = Wsk + (size_t)256 * 768;         // 256*2304
    // nfs [16384, 2304] aliases qb/kb/vb (consumed by proj GEMM before those are written)
    unsigned short* nfs = qb;

    // relevance + split node features (fused), CSR build, graph bounds
    relnf_kernel<<<N_NODES, 256, 0, stream>>>(text, nodex, bid, nfs);
    hipMemsetAsync(cnt, 0, N_NODES * sizeof(int), stream);
    hist_kernel<<<N_EDGES / 256, 256, 0, stream>>>(dst, cnt);
    scan_kernel<<<1, 256, 0, stream>>>(cnt, base, cursor);
    scatter_kernel<<<N_EDGES / 256, 256, 0, stream>>>(src, dst, cursor, esrc, edst);
    gbounds_kernel<<<1, 128, 0, stream>>>(bid, gstart);

    // projection: x = (diag(rel)*nodex) @ Wp + bp (3-term), also emits xs = split(x)
    wconv_kernel<<<dim3(HID / 256, DDIM), 256, 0, stream>>>(Wp, Wps, HID, DDIM);
    gemm_mfma<true><<<dim3(DDIM / 128, N_NODES / 128), 256, 0, stream>>>(
        nfs, Wps, bp, x, xs, DDIM, 3 * HID);
    // tiny text projection stays fp32
    gemm_f32<false><<<dim3(DDIM / 64, 1), 256, 0, stream>>>(
        text, Wp, bp, nullptr, tp64, N_GRAPHS, DDIM, HID);

    for (int i = 0; i < 2; i++) {
        // per-layer weight conversion (qkv 1-term + skip 3-term + biases)
        wconv_layer<<<3328, 256, 0, stream>>>(
            Wq + (size_t)i * DDIM * 1024, Wk + (size_t)i * DDIM * 1024,
            Wv + (size_t)i * DDIM * 1024, Ws + (size_t)i * DDIM * DDIM,
            bq + i * 1024, bk + i * 1024, bv + i * 1024, bs + i * DDIM,
            Wqkv, Wsk, ball);
        // q/k/v: pure bf16 1-term GEMM (K=256), outputs bf16 coalesced
        gemm_qkv<<<dim3(3072 / 128, N_NODES / 128), 256, 0, stream>>>(
            xs, Wqkv, ball, qb, kb, vb);
        // skip: 3-term GEMM (K'=768), fp32 into hbuf
        gemm_mfma<false><<<dim3(DDIM / 128, N_NODES / 128), 256, 0, stream>>>(
            xs, Wsk, ball + 3072, hbuf, nullptr, DDIM, 768);
        // scores at CSR positions (q,k bf16)
        score_csr_kernel<<<N_EDGES, 256, 0, stream>>>(qb, kb, esrc, edst, sc);
        // softmax + gather (v bf16) + head-mean + skip + (resid) + LN + ReLU (+xs for next layer)
        if (i == 0)
            agg_norm_kernel<true, true><<<N_NODES, 256, 0, stream>>>(
                vb, sc, base, cnt, esrc, hbuf, x, xs, gamma, beta);
        else
            agg_norm_kernel<false, false><<<N_NODES, 256, 0, stream>>>(
                vb, sc, base, cnt, esrc, hbuf, x, nullptr, gamma + 256, beta + 256);
    }

    // pools (pstruct, psem, semden contiguous)
    hipMemsetAsync(pstruct, 0, (size_t)(64 * 256 * 2 + 64) * sizeof(float), stream);
    pool1_seg<<<N_GRAPHS * 4, 256, 0, stream>>>(x, tp64, gstart, pstruct, semden, semex);
    pool2_seg<<<N_GRAPHS * 4, 256, 0, stream>>>(x, gstart, semden, semex, psem);
    clf_kernel<<<N_GRAPHS / 4, 256, 0, stream>>>(pstruct, psem, gstart, text, clfw, clfb, out);
}

// Round 5
// 546.935 us; speedup vs baseline: 3.3252x; 1.1168x over previous
//
#include <hip/hip_runtime.h>

#define N_NODES 16384
#define N_EDGES 65536
#define N_GRAPHS 64
#define HID 768
#define DDIM 256
#define HEADS 4

typedef __attribute__((ext_vector_type(8))) short bf16x8;   // 8 bf16 = 4 VGPR (MFMA A/B frag)
typedef __attribute__((ext_vector_type(4))) float f32x4;    // MFMA C/D frag
typedef __attribute__((ext_vector_type(8))) unsigned short u16x8;

// ---------- helpers ----------
__device__ __forceinline__ float wave_reduce_sum(float v) {
#pragma unroll
    for (int off = 32; off; off >>= 1) v += __shfl_xor(v, off);
    return v;
}

__device__ __forceinline__ unsigned short f2bf(float f) {   // RNE fp32 -> bf16 bits
    unsigned u = __float_as_uint(f);
    return (unsigned short)((u + 0x7fffu + ((u >> 16) & 1u)) >> 16);
}
__device__ __forceinline__ float bf2f(unsigned short h) {
    return __uint_as_float((unsigned)h << 16);
}

// ---------- fused cosine relevance + split-bf16 node features ----------
// nfs row layout (1536): [hi(768) | lo(768)] of rel*nodex. (proj re-reads hi for term 3)
__global__ __launch_bounds__(256) void relnf_kernel(
        const float* __restrict__ text, const float* __restrict__ nodex,
        const int* __restrict__ bid, unsigned short* __restrict__ nfs) {
    int n = blockIdx.x, t = threadIdx.x;
    const float* xr = nodex + (size_t)n * HID;
    const float* tr = text + (size_t)bid[n] * HID;
    float xv[3];
    float num = 0.f, tt = 0.f, xx = 0.f;
#pragma unroll
    for (int j = 0; j < 3; j++) {
        int c = t + j * 256;
        float a = xr[c], b = tr[c];
        xv[j] = a; num += a * b; tt += b * b; xx += a * a;
    }
    num = wave_reduce_sum(num);
    tt = wave_reduce_sum(tt);
    xx = wave_reduce_sum(xx);
    __shared__ float s0[4], s1[4], s2[4];
    int lane = t & 63, wv = t >> 6;
    if (lane == 0) { s0[wv] = num; s1[wv] = tt; s2[wv] = xx; }
    __syncthreads();
    num = s0[0] + s0[1] + s0[2] + s0[3];
    tt  = s1[0] + s1[1] + s1[2] + s1[3];
    xx  = s2[0] + s2[1] + s2[2] + s2[3];
    float r = num / fmaxf(sqrtf(tt) * sqrtf(xx), 1e-8f);
    unsigned short* o = nfs + (size_t)n * 1536;
#pragma unroll
    for (int j = 0; j < 3; j++) {
        int c = t + j * 256;
        float a = xv[j] * r;
        unsigned short h = f2bf(a), l = f2bf(a - bf2f(h));
        o[c] = h; o[768 + c] = l;
    }
}

// ---------- W [K,N] f32 -> out [N, 3K] bf16 (B-side block order hi,hi,lo) ----------
__global__ void wconv_kernel(const float* __restrict__ W, unsigned short* __restrict__ out,
                             int K, int N) {
    int k = blockIdx.x * 256 + threadIdx.x;
    int n = blockIdx.y;
    if (k >= K) return;
    float a = W[(size_t)k * N + n];
    unsigned short h = f2bf(a);
    unsigned short l = f2bf(a - bf2f(h));
    size_t o = (size_t)n * (3 * K);
    out[o + k] = h;
    out[o + K + k] = h;
    out[o + 2 * K + k] = l;
}

// ---------- per-layer weights: Wall [3328,256] bf16 1-term (q|k|v|skip), ball [3328] ----------
__global__ void wconv_layer(const float* __restrict__ Wq, const float* __restrict__ Wk,
                            const float* __restrict__ Wv, const float* __restrict__ Ws,
                            const float* __restrict__ bq, const float* __restrict__ bk,
                            const float* __restrict__ bv, const float* __restrict__ bs,
                            unsigned short* __restrict__ Wall, float* __restrict__ ball) {
    int n = blockIdx.x, k = threadIdx.x;          // k in [0,256)
    const float* W; const float* bb; int col, ncols;
    if (n < 1024)      { W = Wq; bb = bq; col = n;        ncols = 1024; }
    else if (n < 2048) { W = Wk; bb = bk; col = n - 1024; ncols = 1024; }
    else if (n < 3072) { W = Wv; bb = bv; col = n - 2048; ncols = 1024; }
    else               { W = Ws; bb = bs; col = n - 3072; ncols = 256; }
    Wall[(size_t)n * 256 + k] = f2bf(W[(size_t)k * ncols + col]);
    if (k == 0) ball[n] = bb[col];
}

// ---------- XCD-chunked block swizzle (m204 bijective) ----------
__device__ __forceinline__ void swz_block(int& bx, int& by) {
    int nwg = gridDim.x * gridDim.y;
    int lin = blockIdx.y * gridDim.x + blockIdx.x;
    int qd = nwg >> 3, rr = nwg & 7;
    int xcd = lin & 7, j = lin >> 3;
    int wg = (xcd < rr ? xcd * (qd + 1) : rr * (qd + 1) + (xcd - rr) * qd) + j;
    bx = wg % gridDim.x;
    by = wg / gridDim.x;
}

// ---------- proj GEMM, 64x64 tiles, 3-term: x[16384,256] = nfs@Wps^T + bp ----------
// A = nfs [16384,1536] (hi|lo); term-3 re-reads hi (k0>=1536 -> k0-1536).
// B = Wps [256, 2304] (hi|hi|lo).  Also emits xb = bf16(x).
__global__ __launch_bounds__(256, 4) void gemm_proj64(
        const unsigned short* __restrict__ A, const unsigned short* __restrict__ B,
        const float* __restrict__ bias, float* __restrict__ x,
        unsigned short* __restrict__ xb) {
    __shared__ unsigned short As[64 * 64];
    __shared__ unsigned short Bs[64 * 64];
    int bx, by; swz_block(bx, by);
    const int tid = threadIdx.x;
    const int lane = tid & 63;
    const int wave = tid >> 6;
    const int wm = wave >> 1, wn = wave & 1;
    const int row0 = by * 64, col0 = bx * 64;
    const int l15 = lane & 15, l16 = lane >> 4;

    f32x4 acc[2][2] = {};
    const char* Ac = (const char*)A;
    const char* Bc = (const char*)B;

    for (int k0 = 0; k0 < 2304; k0 += 64) {
        int ak = (k0 < 1536) ? k0 : (k0 - 1536);
        __syncthreads();
#pragma unroll
        for (int i = 0; i < 2; i++) {           // A-tile 8KB (rows stride 3072B)
            int o = i * 4096 + tid * 16;
            int r = o >> 7, cb = o & 127;
            __builtin_amdgcn_global_load_lds(
                (const __attribute__((address_space(1))) void*)
                    (Ac + (size_t)(row0 + r) * 3072 + ak * 2 + cb),
                (__attribute__((address_space(3))) void*)((char*)As + o), 16, 0, 0);
        }
#pragma unroll
        for (int i = 0; i < 2; i++) {           // B-tile 8KB (rows stride 4608B)
            int o = i * 4096 + tid * 16;
            int r = o >> 7, cb = o & 127;
            __builtin_amdgcn_global_load_lds(
                (const __attribute__((address_space(1))) void*)
                    (Bc + (size_t)(col0 + r) * 4608 + k0 * 2 + cb),
                (__attribute__((address_space(3))) void*)((char*)Bs + o), 16, 0, 0);
        }
        __syncthreads();
#pragma unroll
        for (int kk = 0; kk < 2; kk++) {
            bf16x8 af[2], bfr[2];
#pragma unroll
            for (int f = 0; f < 2; f++) {
                af[f]  = *(const bf16x8*)(As + ((wm * 32 + f * 16 + l15) * 64 + kk * 32 + l16 * 8));
                bfr[f] = *(const bf16x8*)(Bs + ((wn * 32 + f * 16 + l15) * 64 + kk * 32 + l16 * 8));
            }
#pragma unroll
            for (int fi = 0; fi < 2; fi++)
#pragma unroll
                for (int fj = 0; fj < 2; fj++)
                    acc[fi][fj] = __builtin_amdgcn_mfma_f32_16x16x32_bf16(
                        af[fi], bfr[fj], acc[fi][fj], 0, 0, 0);
        }
    }
#pragma unroll
    for (int fj = 0; fj < 2; fj++) {
        int cc = col0 + wn * 32 + fj * 16 + l15;
        float bb = bias[cc];
#pragma unroll
        for (int fi = 0; fi < 2; fi++) {
            int rbase = row0 + wm * 32 + fi * 16 + l16 * 4;
#pragma unroll
            for (int r = 0; r < 4; r++) {
                int row = rbase + r;
                float vv = acc[fi][fj][r] + bb;
                x[(size_t)row * 256 + cc] = vv;
                xb[(size_t)row * 256 + cc] = f2bf(vv);
            }
        }
    }
}

// ---------- fused q/k/v/skip GEMM: [16384,3328] = xb[16384,256] @ Wall^T, all bf16 out ----------
__global__ __launch_bounds__(256, 2) void gemm_qkvsf(
        const unsigned short* __restrict__ A,   // xb [16384,256]
        const unsigned short* __restrict__ B,   // Wall [3328,256]
        const float* __restrict__ ball,
        unsigned short* __restrict__ qb, unsigned short* __restrict__ kb,
        unsigned short* __restrict__ vb, unsigned short* __restrict__ hb) {
    __shared__ unsigned short smem[128 * 128];  // As | Bs during K-loop, C-tile after
    unsigned short* As = smem;
    unsigned short* Bs = smem + 128 * 64;
    int bx, by; swz_block(bx, by);
    const int tid = threadIdx.x;
    const int lane = tid & 63;
    const int wave = tid >> 6;
    const int wm = wave >> 1, wn = wave & 1;
    const int row0 = by * 128, col0 = bx * 128;
    const int l15 = lane & 15, l16 = lane >> 4;

    f32x4 acc[4][4] = {};
    const char* Ac = (const char*)A;
    const char* Bc = (const char*)B;

    for (int k0 = 0; k0 < 256; k0 += 64) {
        __syncthreads();
#pragma unroll
        for (int i = 0; i < 4; i++) {           // A: rows stride 512B
            int o = i * 4096 + tid * 16;
            int r = o >> 7, cb = o & 127;
            __builtin_amdgcn_global_load_lds(
                (const __attribute__((address_space(1))) void*)
                    (Ac + (size_t)(row0 + r) * 512 + k0 * 2 + cb),
                (__attribute__((address_space(3))) void*)((char*)As + o), 16, 0, 0);
        }
#pragma unroll
        for (int i = 0; i < 4; i++) {           // B: rows stride 512B
            int o = i * 4096 + tid * 16;
            int r = o >> 7, cb = o & 127;
            __builtin_amdgcn_global_load_lds(
                (const __attribute__((address_space(1))) void*)
                    (Bc + (size_t)(col0 + r) * 512 + k0 * 2 + cb),
                (__attribute__((address_space(3))) void*)((char*)Bs + o), 16, 0, 0);
        }
        __syncthreads();
#pragma unroll
        for (int kk = 0; kk < 2; kk++) {
            bf16x8 af[4], bfr[4];
#pragma unroll
            for (int f = 0; f < 4; f++) {
                af[f]  = *(const bf16x8*)(As + ((wm * 64 + f * 16 + l15) * 64 + kk * 32 + l16 * 8));
                bfr[f] = *(const bf16x8*)(Bs + ((wn * 64 + f * 16 + l15) * 64 + kk * 32 + l16 * 8));
            }
#pragma unroll
            for (int fi = 0; fi < 4; fi++)
#pragma unroll
                for (int fj = 0; fj < 4; fj++)
                    acc[fi][fj] = __builtin_amdgcn_mfma_f32_16x16x32_bf16(
                        af[fi], bfr[fj], acc[fi][fj], 0, 0, 0);
        }
    }
    __syncthreads();                // all waves done reading As/Bs; reuse as C-stage
    // stage bf16 C-tile to LDS with 16B-chunk row-XOR swizzle
#pragma unroll
    for (int fj = 0; fj < 4; fj++) {
        int cl = wn * 64 + fj * 16 + l15;       // local col 0..127
        float bb = ball[col0 + cl];
#pragma unroll
        for (int fi = 0; fi < 4; fi++) {
#pragma unroll
            for (int r = 0; r < 4; r++) {
                int rl = wm * 64 + fi * 16 + l16 * 4 + r;   // local row 0..127
                int chunk = (cl >> 3) ^ (rl & 15);
                smem[rl * 128 + chunk * 8 + (cl & 7)] = f2bf(acc[fi][fj][r] + bb);
            }
        }
    }
    __syncthreads();
    // coalesced store: thread writes 128B contiguous of one row
    int seg = col0 >> 10;           // 0=q, 1=k, 2=v, 3=skip (block-uniform)
    int rl = tid >> 1, half = tid & 1;
    unsigned short* dstp;
    if (seg == 0)      dstp = qb + (size_t)(row0 + rl) * 1024 + (col0 & 1023) + half * 64;
    else if (seg == 1) dstp = kb + (size_t)(row0 + rl) * 1024 + (col0 & 1023) + half * 64;
    else if (seg == 2) dstp = vb + (size_t)(row0 + rl) * 1024 + (col0 & 1023) + half * 64;
    else               dstp = hb + (size_t)(row0 + rl) * 256 + (col0 - 3072) + half * 64;
#pragma unroll
    for (int i = 0; i < 8; i++) {
        int chunk = (half * 8 + i) ^ (rl & 15);
        ((u16x8*)dstp)[i] = *(const u16x8*)(smem + rl * 128 + chunk * 8);
    }
}

// ---------- generic fp32 tiled GEMM (tiny 64x256 tp GEMM only) ----------
template<bool SCALE_A>
__global__ __launch_bounds__(256) void gemm_f32(
        const float* __restrict__ A, const float* __restrict__ B,
        const float* __restrict__ bias, const float* __restrict__ rowScale,
        float* __restrict__ C, int M, int N, int K) {
    const int BM = 64, BN = 64, BK = 16;
    __shared__ float As[BK][BM + 1];
    __shared__ float Bs[BK][BN + 1];
    int tid = threadIdx.x;
    int tx = tid & 15, ty = tid >> 4;
    int row0 = blockIdx.y * BM, col0 = blockIdx.x * BN;
    float acc[4][4] = {};
    for (int k0 = 0; k0 < K; k0 += BK) {
        {
            int c = tid & 15, r = tid >> 4;
#pragma unroll
            for (int i = 0; i < 4; i++) {
                int rr = r + 16 * i;
                float a = A[(size_t)(row0 + rr) * K + k0 + c];
                if (SCALE_A) a *= rowScale[row0 + rr];
                As[c][rr] = a;
            }
        }
        {
            int c = tid & 63, kr = tid >> 6;
#pragma unroll
            for (int i = 0; i < 4; i++) {
                int rr = kr + 4 * i;
                Bs[rr][c] = B[(size_t)(k0 + rr) * N + col0 + c];
            }
        }
        __syncthreads();
#pragma unroll
        for (int kk = 0; kk < BK; kk++) {
            float av[4], bv[4];
#pragma unroll
            for (int i = 0; i < 4; i++) av[i] = As[kk][ty * 4 + i];
#pragma unroll
            for (int j = 0; j < 4; j++) bv[j] = Bs[kk][tx * 4 + j];
#pragma unroll
            for (int i = 0; i < 4; i++)
#pragma unroll
                for (int j = 0; j < 4; j++)
                    acc[i][j] += av[i] * bv[j];
        }
        __syncthreads();
    }
#pragma unroll
    for (int i = 0; i < 4; i++) {
        int r = row0 + ty * 4 + i;
#pragma unroll
        for (int j = 0; j < 4; j++) {
            int c = col0 + tx * 4 + j;
            C[(size_t)r * N + c] = acc[i][j] + bias[c];
        }
    }
}

// ---------- CSR build ----------
__global__ void hist_kernel(const int* __restrict__ dst, int* __restrict__ cnt) {
    int e = blockIdx.x * 256 + threadIdx.x;
    if (e < N_EDGES) atomicAdd(&cnt[dst[e]], 1);
}

__global__ void scan_kernel(const int* __restrict__ cnt, int* __restrict__ base,
                            int* __restrict__ cursor) {
    int t = threadIdx.x;
    int s = 0;
    for (int i = 0; i < 64; i++) s += cnt[t * 64 + i];
    __shared__ int pref[256];
    pref[t] = s;
    __syncthreads();
    if (t == 0) {
        int a = 0;
        for (int i = 0; i < 256; i++) { int v = pref[i]; pref[i] = a; a += v; }
    }
    __syncthreads();
    int run = pref[t];
    for (int i = 0; i < 64; i++) {
        base[t * 64 + i] = run;
        cursor[t * 64 + i] = run;
        run += cnt[t * 64 + i];
    }
}

__global__ void scatter_kernel(const int* __restrict__ src, const int* __restrict__ dst,
                               int* __restrict__ cursor, int* __restrict__ esrc,
                               int* __restrict__ edst) {
    int e = blockIdx.x * 256 + threadIdx.x;
    if (e < N_EDGES) {
        int d = dst[e];
        int pos = atomicAdd(&cursor[d], 1);
        esrc[pos] = src[e];
        edst[pos] = d;
    }
}

// ---------- graph segment boundaries (batch_ids is sorted) ----------
__global__ void gbounds_kernel(const int* __restrict__ bid, int* __restrict__ gstart) {
    int g = threadIdx.x;
    if (g > N_GRAPHS) return;
    int lo = 0, hi = N_NODES;
    while (lo < hi) { int mid = (lo + hi) >> 1; if (bid[mid] < g) lo = mid + 1; else hi = mid; }
    gstart[g] = lo;
}

// ---------- edge scores at CSR positions: q bf16 · k bf16 ----------
__global__ void score_csr_kernel(const unsigned short* __restrict__ qb,
                                 const unsigned short* __restrict__ kb,
                                 const int* __restrict__ esrc, const int* __restrict__ edst,
                                 float* __restrict__ sc) {
    int w = blockIdx.x * 4 + (threadIdx.x >> 6);
    int lane = threadIdx.x & 63;
    int pos = w >> 2, h = w & 3;
    int s = esrc[pos], d = edst[pos];
    ushort4 qa = ((const ushort4*)(qb + (size_t)d * 1024 + h * 256))[lane];
    ushort4 ka = ((const ushort4*)(kb + (size_t)s * 1024 + h * 256))[lane];
    float p = bf2f(qa.x) * bf2f(ka.x) + bf2f(qa.y) * bf2f(ka.y)
            + bf2f(qa.z) * bf2f(ka.z) + bf2f(qa.w) * bf2f(ka.w);
    p = wave_reduce_sum(p);
    if (lane == 0) sc[(size_t)pos * 4 + h] = p * 0.0625f;  // 1/sqrt(256)
}

// ---------- per-node: softmax + alpha*v gather (bf16) + head-mean + skip(bf16) (+resid) + LN + ReLU ----------
template<bool RESID, bool WXB>
__global__ __launch_bounds__(256) void agg_norm_kernel(
        const unsigned short* __restrict__ vb, const float* __restrict__ sc,
        const int* __restrict__ base, const int* __restrict__ cnt,
        const int* __restrict__ esrc, const unsigned short* __restrict__ hb,
        float* __restrict__ x, unsigned short* __restrict__ xb,
        const float* __restrict__ gamma, const float* __restrict__ beta) {
    __shared__ float hacc[4][256];
    __shared__ float tmp[4];
    int n = blockIdx.x;
    int tid = threadIdx.x, lane = tid & 63, h = tid >> 6;
    int start = base[n], deg = cnt[n];

    float m = -1e30f;
    for (int i = 0; i < deg; i++) m = fmaxf(m, sc[(size_t)(start + i) * 4 + h]);
    if (deg == 0) m = 0.f;
    float den = 0.f;
    for (int i = 0; i < deg; i++) den += __expf(sc[(size_t)(start + i) * 4 + h] - m);
    float inv_den = 0.25f / (den + 1e-16f);

    float4 acc = {0.f, 0.f, 0.f, 0.f};
    for (int i = 0; i < deg; i++) {
        int s = esrc[start + i];
        float a = __expf(sc[(size_t)(start + i) * 4 + h] - m) * inv_den;
        ushort4 vv = ((const ushort4*)(vb + (size_t)s * 1024 + h * 256))[lane];
        acc.x += a * bf2f(vv.x); acc.y += a * bf2f(vv.y);
        acc.z += a * bf2f(vv.z); acc.w += a * bf2f(vv.w);
    }
    ((float4*)&hacc[h][lane * 4])[0] = acc;
    __syncthreads();

    int c = tid;
    float val = hacc[0][c] + hacc[1][c] + hacc[2][c] + hacc[3][c]
              + bf2f(hb[(size_t)n * 256 + c]);
    if (RESID) val += x[(size_t)n * 256 + c];

    float s1 = wave_reduce_sum(val);
    if (lane == 0) tmp[h] = s1;
    __syncthreads();
    float mu = (tmp[0] + tmp[1] + tmp[2] + tmp[3]) * (1.0f / 256.0f);
    __syncthreads();
    float d = val - mu;
    float s2 = wave_reduce_sum(d * d);
    if (lane == 0) tmp[h] = s2;
    __syncthreads();
    float inv = rsqrtf((tmp[0] + tmp[1] + tmp[2] + tmp[3]) * (1.0f / 256.0f) + 1e-5f);
    float o = fmaxf(d * inv * gamma[c] + beta[c], 0.f);
    x[(size_t)n * 256 + c] = o;
    if (WXB) xb[(size_t)n * 256 + c] = f2bf(o);
}

// ---------- pooling pass 1 (segmented) ----------
__global__ __launch_bounds__(256) void pool1_seg(
        const float* __restrict__ x, const float* __restrict__ tp,
        const int* __restrict__ gstart, float* __restrict__ pstruct,
        float* __restrict__ semden, float* __restrict__ semex) {
    int g = blockIdx.x >> 2, q = blockIdx.x & 3;
    int s0 = gstart[g], s1 = gstart[g + 1];
    int chunk = (s1 - s0 + 3) >> 2;
    int a = s0 + q * chunk, b = min(a + chunk, s1);
    int wave = threadIdx.x >> 6, lane = threadIdx.x & 63;
    float4 tv = ((const float4*)(tp + (size_t)g * 256))[lane];
    float4 acc = {0.f, 0.f, 0.f, 0.f};
    float esum = 0.f;
    for (int n = a + wave; n < b; n += 4) {
        float4 xv = ((const float4*)(x + (size_t)n * 256))[lane];
        float p = wave_reduce_sum(xv.x * tv.x + xv.y * tv.y + xv.z * tv.z + xv.w * tv.w);
        float e = __expf(p);
        if (lane == 0) semex[n] = e;
        esum += e;
        acc.x += xv.x; acc.y += xv.y; acc.z += xv.z; acc.w += xv.w;
    }
    __shared__ float sacc[4][256];
    __shared__ float tse[4];
    ((float4*)&sacc[wave][lane * 4])[0] = acc;
    if (lane == 0) tse[wave] = esum;
    __syncthreads();
    int c = threadIdx.x;
    float v = sacc[0][c] + sacc[1][c] + sacc[2][c] + sacc[3][c];
    atomicAdd(&pstruct[(size_t)g * 256 + c], v);
    if (threadIdx.x == 0)
        atomicAdd(&semden[g], tse[0] + tse[1] + tse[2] + tse[3]);
}

// ---------- pooling pass 2 (segmented) ----------
__global__ __launch_bounds__(256) void pool2_seg(
        const float* __restrict__ x, const int* __restrict__ gstart,
        const float* __restrict__ semden, const float* __restrict__ semex,
        float* __restrict__ psem) {
    int g = blockIdx.x >> 2, q = blockIdx.x & 3;
    int s0 = gstart[g], s1 = gstart[g + 1];
    int chunk = (s1 - s0 + 3) >> 2;
    int a = s0 + q * chunk, b = min(a + chunk, s1);
    int wave = threadIdx.x >> 6, lane = threadIdx.x & 63;
    float inv = 1.0f / (semden[g] + 1e-8f);
    float4 acc = {0.f, 0.f, 0.f, 0.f};
    for (int n = a + wave; n < b; n += 4) {
        float aw = semex[n] * inv;
        float4 xv = ((const float4*)(x + (size_t)n * 256))[lane];
        acc.x += xv.x * aw; acc.y += xv.y * aw; acc.z += xv.z * aw; acc.w += xv.w * aw;
    }
    __shared__ float sacc[4][256];
    ((float4*)&sacc[wave][lane * 4])[0] = acc;
    __syncthreads();
    int c = threadIdx.x;
    float v = sacc[0][c] + sacc[1][c] + sacc[2][c] + sacc[3][c];
    atomicAdd(&psem[(size_t)g * 256 + c], v);
}

// ---------- classifier ----------
__global__ void clf_kernel(const float* __restrict__ pstruct, const float* __restrict__ psem,
                           const int* __restrict__ gstart, const float* __restrict__ text,
                           const float* __restrict__ w, const float* __restrict__ b,
                           float* __restrict__ out) {
    int g = blockIdx.x * 4 + (threadIdx.x >> 6);
    int lane = threadIdx.x & 63;
    float invc = 1.0f / fmaxf((float)(gstart[g + 1] - gstart[g]), 1.0f);
    float acc = 0.f;
#pragma unroll
    for (int i = 0; i < 4; i++) { int c = lane + i * 64; acc += pstruct[(size_t)g * 256 + c] * invc * w[c]; }
#pragma unroll
    for (int i = 0; i < 4; i++) { int c = lane + i * 64; acc += psem[(size_t)g * 256 + c] * w[256 + c]; }
#pragma unroll
    for (int i = 0; i < 12; i++) { int c = lane + i * 64; acc += text[(size_t)g * 768 + c] * w[512 + c]; }
    acc = wave_reduce_sum(acc);
    if (lane == 0) out[g] = acc + b[0];
}

extern "C" void kernel_launch(void* const* d_in, const int* in_sizes, int n_in,
                              void* d_out, int out_size, void* d_ws, size_t ws_size,
                              hipStream_t stream) {
    const float* text  = (const float*)d_in[0];
    const float* nodex = (const float*)d_in[1];
    const float* Wp    = (const float*)d_in[2];
    const float* bp    = (const float*)d_in[3];
    const float* Wq    = (const float*)d_in[4];
    const float* bq    = (const float*)d_in[5];
    const float* Wk    = (const float*)d_in[6];
    const float* bk    = (const float*)d_in[7];
    const float* Wv    = (const float*)d_in[8];
    const float* bv    = (const float*)d_in[9];
    const float* Ws    = (const float*)d_in[10];
    const float* bs    = (const float*)d_in[11];
    const float* gamma = (const float*)d_in[12];
    const float* beta  = (const float*)d_in[13];
    const float* clfw  = (const float*)d_in[14];
    const float* clfb  = (const float*)d_in[15];
    const int*   eidx  = (const int*)d_in[16];
    const int*   bid   = (const int*)d_in[17];
    const int* src = eidx;
    const int* dst = eidx + N_EDGES;
    float* out = (float*)d_out;

    // workspace layout
    float* x     = (float*)d_ws;                     // 16384*256 f32
    float* tp64  = x + (size_t)N_NODES * 256;        // 64*256
    float* sc    = tp64 + 64 * 256;                  // 65536*4
    float* semex = sc + (size_t)N_EDGES * 4;         // 16384
    float* pstruct = semex + N_NODES;                // 64*256
    float* psem  = pstruct + 64 * 256;               // 64*256
    float* semden = psem + 64 * 256;                 // 64
    float* ball  = semden + 64;                      // 3328
    int* esrc    = (int*)(ball + 3328);              // 65536
    int* edst    = esrc + N_EDGES;                   // 65536
    int* cnt     = edst + N_EDGES;                   // 16384
    int* base    = cnt + N_NODES;                    // 16384
    int* cursor  = base + N_NODES;                   // 16384
    int* gstart  = cursor + N_NODES;                 // 80 (65 used)
    unsigned short* qb   = (unsigned short*)(gstart + 80);  // 16384*1024 bf16
    unsigned short* kb   = qb + (size_t)N_NODES * 1024;     // 16384*1024
    unsigned short* vb   = kb + (size_t)N_NODES * 1024;     // 16384*1024
    unsigned short* hb   = vb + (size_t)N_NODES * 1024;     // 16384*256 bf16 (skip)
    unsigned short* xb   = hb + (size_t)N_NODES * 256;      // 16384*256 bf16
    unsigned short* Wall = xb + (size_t)N_NODES * 256;      // 3328*256
    unsigned short* Wps  = Wall + (size_t)3328 * 256;       // 256*2304
    // nfs [16384,1536] aliases qb+kb (consumed by proj GEMM before those are written)
    unsigned short* nfs = qb;

    // relevance + split node features (fused), CSR build, graph bounds
    relnf_kernel<<<N_NODES, 256, 0, stream>>>(text, nodex, bid, nfs);
    hipMemsetAsync(cnt, 0, N_NODES * sizeof(int), stream);
    hist_kernel<<<N_EDGES / 256, 256, 0, stream>>>(dst, cnt);
    scan_kernel<<<1, 256, 0, stream>>>(cnt, base, cursor);
    scatter_kernel<<<N_EDGES / 256, 256, 0, stream>>>(src, dst, cursor, esrc, edst);
    gbounds_kernel<<<1, 128, 0, stream>>>(bid, gstart);

    // projection: x = (diag(rel)*nodex) @ Wp + bp (3-term, 64x64 tiles), emits xb = bf16(x)
    wconv_kernel<<<dim3(HID / 256, DDIM), 256, 0, stream>>>(Wp, Wps, HID, DDIM);
    gemm_proj64<<<dim3(DDIM / 64, N_NODES / 64), 256, 0, stream>>>(nfs, Wps, bp, x, xb);
    // tiny text projection stays fp32
    gemm_f32<false><<<dim3(DDIM / 64, 1), 256, 0, stream>>>(
        text, Wp, bp, nullptr, tp64, N_GRAPHS, DDIM, HID);

    for (int i = 0; i < 2; i++) {
        // per-layer weight conversion (q|k|v|skip 1-term + biases)
        wconv_layer<<<3328, 256, 0, stream>>>(
            Wq + (size_t)i * DDIM * 1024, Wk + (size_t)i * DDIM * 1024,
            Wv + (size_t)i * DDIM * 1024, Ws + (size_t)i * DDIM * DDIM,
            bq + i * 1024, bk + i * 1024, bv + i * 1024, bs + i * DDIM,
            Wall, ball);
        // fused q/k/v/skip GEMM (K=256, all-bf16 outputs, LDS-staged coalesced stores)
        gemm_qkvsf<<<dim3(3328 / 128, N_NODES / 128), 256, 0, stream>>>(
            xb, Wall, ball, qb, kb, vb, hb);
        // scores at CSR positions (q,k bf16)
        score_csr_kernel<<<N_EDGES, 256, 0, stream>>>(qb, kb, esrc, edst, sc);
        // softmax + gather (v bf16) + head-mean + skip(bf16) + (resid) + LN + ReLU (+xb)
        if (i == 0)
            agg_norm_kernel<true, true><<<N_NODES, 256, 0, stream>>>(
                vb, sc, base, cnt, esrc, hb, x, xb, gamma, beta);
        else
            agg_norm_kernel<false, false><<<N_NODES, 256, 0, stream>>>(
                vb, sc, base, cnt, esrc, hb, x, nullptr, gamma + 256, beta + 256);
    }

    // pools (pstruct, psem, semden contiguous)
    hipMemsetAsync(pstruct, 0, (size_t)(64 * 256 * 2 + 64) * sizeof(float), stream);
    pool1_seg<<<N_GRAPHS * 4, 256, 0, stream>>>(x, tp64, gstart, pstruct, semden, semex);
    pool2_seg<<<N_GRAPHS * 4, 256, 0, stream>>>(x, gstart, semden, semex, psem);
    clf_kernel<<<N_GRAPHS / 4, 256, 0, stream>>>(pstruct, psem, gstart, text, clfw, clfb, out);
}